// Round 9
// baseline (402.203 us; speedup 1.0000x reference)
//
#include <hip/hip_runtime.h>
#include <math.h>

typedef __attribute__((ext_vector_type(8))) short short8;
typedef __attribute__((ext_vector_type(4))) float f32x4;

#define LN_EPS 1e-5f

__device__ __forceinline__ float bf2f(unsigned short u) {
  unsigned int x = ((unsigned int)u) << 16;
  float f;
  __builtin_memcpy(&f, &x, 4);
  return f;
}
__device__ __forceinline__ unsigned short f2bf(float f) {
  unsigned int x;
  __builtin_memcpy(&x, &f, 4);
  x += 0x7fffu + ((x >> 16) & 1u);
  return (unsigned short)(x >> 16);
}

__device__ __forceinline__ void gload16(const void* g, void* l) {
  __builtin_amdgcn_global_load_lds(
      (__attribute__((address_space(1))) void*)(void*)g,
      (__attribute__((address_space(3))) void*)l, 16, 0, 0);
}

// bijective chunked XCD swizzle (requires nx*ny % 8 == 0)
__device__ __forceinline__ void xcd_swizzle(int& bx, int& by) {
  const int nx = gridDim.x;
  const int nwg = nx * gridDim.y;
  const int orig = blockIdx.y * nx + blockIdx.x;
  const int cpx = nwg >> 3;
  const int lid = (orig & 7) * cpx + (orig >> 3);
  bx = lid % nx;
  by = lid / nx;
}

// ---------------- block reduce (sum, sumsq) over 256 threads ----------------
__device__ __forceinline__ void blockReduce2(float& a, float& b, float* s8) {
#pragma unroll
  for (int off = 32; off > 0; off >>= 1) {
    a += __shfl_down(a, off);
    b += __shfl_down(b, off);
  }
  const int w = threadIdx.x >> 6;
  if ((threadIdx.x & 63) == 0) { s8[w] = a; s8[4 + w] = b; }
  __syncthreads();
  a = s8[0] + s8[1] + s8[2] + s8[3];
  b = s8[4] + s8[5] + s8[6] + s8[7];
}

// ---------------- LN of q,k,v -> bf16 ----------------
__global__ __launch_bounds__(256) void ln3_kernel(
    const float* __restrict__ q, const float* __restrict__ k, const float* __restrict__ v,
    const float* __restrict__ gq, const float* __restrict__ bq,
    const float* __restrict__ gk, const float* __restrict__ bk,
    const float* __restrict__ gv, const float* __restrict__ bv,
    unsigned short* __restrict__ oq, unsigned short* __restrict__ ok,
    unsigned short* __restrict__ ov) {
  __shared__ float s8[8];
  const int row = blockIdx.x, which = blockIdx.y;
  const float* x = which == 0 ? q : which == 1 ? k : v;
  const float* g = which == 0 ? gq : which == 1 ? gk : gv;
  const float* b = which == 0 ? bq : which == 1 ? bk : bv;
  unsigned short* o = which == 0 ? oq : which == 1 ? ok : ov;
  const float4 xv = ((const float4*)(x + (size_t)row * 1024))[threadIdx.x];
  float s = xv.x + xv.y + xv.z + xv.w;
  float s2 = xv.x * xv.x + xv.y * xv.y + xv.z * xv.z + xv.w * xv.w;
  blockReduce2(s, s2, s8);
  const float mu = s * (1.f / 1024.f);
  const float rs = rsqrtf(s2 * (1.f / 1024.f) - mu * mu + LN_EPS);
  const int c = threadIdx.x * 4;
  const float y[4] = {xv.x, xv.y, xv.z, xv.w};
#pragma unroll
  for (int j = 0; j < 4; ++j)
    o[(size_t)row * 1024 + c + j] = f2bf((y[j] - mu) * rs * g[c + j] + b[c + j]);
}

// ------- fused: LN(q_res) -> xf,xb AND router logits/softmax/top2 (NO atomics) -------
__global__ __launch_bounds__(256) void ln_moe_router_kernel(
    const float* __restrict__ qres, const float* __restrict__ g, const float* __restrict__ b,
    const float* __restrict__ Wr, const float* __restrict__ br,
    const float* __restrict__ noise,
    float* __restrict__ xf, unsigned short* __restrict__ xb,
    int* __restrict__ pick, float* __restrict__ pw) {
  __shared__ float s8[8];
  __shared__ float sacc[32];
  const int row = blockIdx.x;
  const float4 xv = ((const float4*)(qres + (size_t)row * 1024))[threadIdx.x];
  float s = xv.x + xv.y + xv.z + xv.w;
  float s2 = xv.x * xv.x + xv.y * xv.y + xv.z * xv.z + xv.w * xv.w;
  blockReduce2(s, s2, s8);
  const float mu = s * (1.f / 1024.f);
  const float rs = rsqrtf(s2 * (1.f / 1024.f) - mu * mu + LN_EPS);
  const int c = threadIdx.x * 4;
  const float yin[4] = {xv.x, xv.y, xv.z, xv.w};
  float y[4];
#pragma unroll
  for (int j = 0; j < 4; ++j) {
    y[j] = (yin[j] - mu) * rs * g[c + j] + b[c + j];
    xf[(size_t)row * 1024 + c + j] = y[j];
    xb[(size_t)row * 1024 + c + j] = f2bf(y[j]);
  }
  float acc[8] = {};
  const float4* wrv = (const float4*)(Wr + (size_t)c * 8);
#pragma unroll
  for (int j = 0; j < 4; ++j) {
    const float4 w0 = wrv[j * 2], w1 = wrv[j * 2 + 1];
    acc[0] += y[j] * w0.x; acc[1] += y[j] * w0.y;
    acc[2] += y[j] * w0.z; acc[3] += y[j] * w0.w;
    acc[4] += y[j] * w1.x; acc[5] += y[j] * w1.y;
    acc[6] += y[j] * w1.z; acc[7] += y[j] * w1.w;
  }
#pragma unroll
  for (int off = 32; off > 0; off >>= 1)
#pragma unroll
    for (int e = 0; e < 8; ++e) acc[e] += __shfl_down(acc[e], off);
  const int w = threadIdx.x >> 6;
  if ((threadIdx.x & 63) == 0)
#pragma unroll
    for (int e = 0; e < 8; ++e) sacc[w * 8 + e] = acc[e];
  __syncthreads();
  if (threadIdx.x == 0) {
    float lg[8], mx = -1e30f;
#pragma unroll
    for (int e = 0; e < 8; ++e) {
      lg[e] = sacc[e] + sacc[8 + e] + sacc[16 + e] + sacc[24 + e] + br[e] +
              0.1f * noise[(size_t)row * 8 + e];
      mx = fmaxf(mx, lg[e]);
    }
    float ssum = 0.f;
#pragma unroll
    for (int e = 0; e < 8; ++e) { lg[e] = expf(lg[e] - mx); ssum += lg[e]; }
    const float inv = 1.f / ssum;
#pragma unroll
    for (int e = 0; e < 8; ++e) lg[e] *= inv;
    int i1 = -1, i2 = -1;
    float m1 = -1.f, m2 = -1.f;
#pragma unroll
    for (int e = 0; e < 8; ++e) {
      if (lg[e] > m1) { m2 = m1; i2 = i1; m1 = lg[e]; i1 = e; }
      else if (lg[e] > m2) { m2 = lg[e]; i2 = e; }
    }
    pick[row * 2] = i1; pick[row * 2 + 1] = i2;
    pw[row * 2] = m1;  pw[row * 2 + 1] = m2;
  }
}

// ------- single-block routing build (LDS atomics only), pad-to-128 -------
__global__ __launch_bounds__(1024) void route_build_kernel(
    const int* __restrict__ pick, const float* __restrict__ pw,
    int* __restrict__ seg, int* __restrict__ tok, float* __restrict__ wgt,
    int* __restrict__ slt) {
  __shared__ int cnt[8];
  __shared__ int segs[9];
  __shared__ int cur[8];
  const int tid = threadIdx.x;
  if (tid < 8) { cnt[tid] = 0; cur[tid] = 0; }
  __syncthreads();
  for (int i = tid; i < 8192; i += 1024) atomicAdd(&cnt[pick[i]], 1);
  __syncthreads();
  if (tid == 0) {
    int o = 0;
    for (int e = 0; e < 8; ++e) { segs[e] = o; o += (cnt[e] + 127) & ~127; }
    segs[8] = o;
  }
  __syncthreads();
  for (int i = tid; i < 9216; i += 1024) tok[i] = -1;
  if (tid < 9) seg[tid] = segs[tid];
  __syncthreads();
  for (int i = tid; i < 8192; i += 1024) {
    const int n = i >> 1, sl = i & 1;
    const int e = pick[i];
    const int p = atomicAdd(&cur[e], 1);
    const int gr = segs[e] + p;
    tok[gr] = n;
    wgt[gr] = pw[i];
    slt[gr] = sl;
  }
}

// ------- final: out = qres + LN(eo0 + eo1 + x); expert slots in bf16 -------
__global__ __launch_bounds__(256) void final_kernel(
    const unsigned short* __restrict__ eoSb, const float* __restrict__ xf,
    const float* __restrict__ qres, const float* __restrict__ g,
    const float* __restrict__ b, float* __restrict__ out) {
  __shared__ float s8[8];
  const int row = blockIdx.x;
  const size_t SLOT = (size_t)4096 * 1024;
  const unsigned short* p0 = eoSb + (size_t)row * 1024 + threadIdx.x * 4;
  const unsigned short* p1 = eoSb + SLOT + (size_t)row * 1024 + threadIdx.x * 4;
  const float4 xv = ((const float4*)(xf + (size_t)row * 1024))[threadIdx.x];
  float y[4];
#pragma unroll
  for (int j = 0; j < 4; ++j) y[j] = bf2f(p0[j]) + bf2f(p1[j]);
  y[0] += xv.x; y[1] += xv.y; y[2] += xv.z; y[3] += xv.w;
  float s = y[0] + y[1] + y[2] + y[3];
  float s2 = y[0] * y[0] + y[1] * y[1] + y[2] * y[2] + y[3] * y[3];
  blockReduce2(s, s2, s8);
  const float mu = s * (1.f / 1024.f);
  const float rs = rsqrtf(s2 * (1.f / 1024.f) - mu * mu + LN_EPS);
  const int c = threadIdx.x * 4;
#pragma unroll
  for (int j = 0; j < 4; ++j) {
    const size_t idx = (size_t)row * 1024 + c + j;
    out[idx] = qres[idx] + (y[j] - mu) * rs * g[c + j] + b[c + j];
  }
}

// ------- batched transpose + f32->bf16 -------
__global__ __launch_bounds__(256) void transposeB_kernel(
    const float* const* __restrict__ ins, unsigned short* const* __restrict__ outs,
    int R, int C) {
  __shared__ float t[32][33];
  const float* inz = ins[blockIdx.z];
  unsigned short* outz = outs[blockIdx.z];
  const int bx = blockIdx.x, by = blockIdx.y;
  const int tx = threadIdx.x & 31, ty = threadIdx.x >> 5;
#pragma unroll
  for (int i = 0; i < 32; i += 8)
    t[ty + i][tx] = inz[(size_t)(by * 32 + ty + i) * C + bx * 32 + tx];
  __syncthreads();
#pragma unroll
  for (int i = 0; i < 32; i += 8)
    outz[(size_t)(bx * 32 + ty + i) * R + by * 32 + tx] = f2bf(t[tx][ty + i]);
}

__global__ __launch_bounds__(256) void transpose8_kernel(
    const float* __restrict__ in, unsigned short* __restrict__ out, int R, int C) {
  __shared__ float t[32][33];
  const float* inz = in + (size_t)blockIdx.z * R * C;
  unsigned short* outz = out + (size_t)blockIdx.z * R * C;
  const int bx = blockIdx.x, by = blockIdx.y;
  const int tx = threadIdx.x & 31, ty = threadIdx.x >> 5;
#pragma unroll
  for (int i = 0; i < 32; i += 8)
    t[ty + i][tx] = inz[(size_t)(by * 32 + ty + i) * C + bx * 32 + tx];
  __syncthreads();
#pragma unroll
  for (int i = 0; i < 32; i += 8)
    outz[(size_t)(bx * 32 + ty + i) * R + by * 32 + tx] = f2bf(t[tx][ty + i]);
}

// ========== Core A: 128x128 tile, BK=32, 256 thr, dbuf (r5 proven) ==========
#define GEMM_STAGE(buf, k0, KD)                                              \
  gload16(gA0 + (k0), lA + (buf) * 4096);                                    \
  gload16(gA1 + (k0), lA + (buf) * 4096 + 16 * 32);                          \
  gload16(gB + (k0), lB + (buf) * 4096);                                     \
  gload16(gB + (size_t)16 * (KD) + (k0), lB + (buf) * 4096 + 16 * 32);

#define GEMM_COMPUTE(buf)                                                    \
  {                                                                          \
    const unsigned short* sA = &As[buf][0];                                  \
    const unsigned short* sB = &Bs[buf][0];                                  \
    short8 af[4], bfr[4];                                                    \
    _Pragma("unroll") for (int m = 0; m < 4; ++m)                            \
        af[m] = *(const short8*)&sA[(arow + m * 16) * 32 + kk];              \
    _Pragma("unroll") for (int n = 0; n < 4; ++n)                            \
        bfr[n] = *(const short8*)&sB[(brow + n * 16) * 32 + kk];             \
    _Pragma("unroll") for (int m = 0; m < 4; ++m)                            \
      _Pragma("unroll") for (int n = 0; n < 4; ++n)                          \
        acc[m][n] = __builtin_amdgcn_mfma_f32_16x16x32_bf16(                 \
            af[m], bfr[n], acc[m][n], 0, 0, 0);                              \
  }

#define GEMM_LOOP(KD)                                                        \
  GEMM_STAGE(0, 0, KD)                                                       \
  __syncthreads();                                                           \
  for (int k0 = 0; k0 < (KD); k0 += 64) {                                    \
    GEMM_STAGE(1, k0 + 32, KD)                                               \
    GEMM_COMPUTE(0)                                                          \
    __syncthreads();                                                         \
    if (k0 + 64 < (KD)) { GEMM_STAGE(0, k0 + 64, KD) }                       \
    GEMM_COMPUTE(1)                                                          \
    __syncthreads();                                                         \
  }

#define GEMM_PREAMBLE                                                        \
  __shared__ __align__(16) unsigned short As[2][128 * 32];                   \
  __shared__ __align__(16) unsigned short Bs[2][128 * 32];                   \
  const int tid = threadIdx.x;                                               \
  const int lane = tid & 63, w = tid >> 6;                                   \
  const int wr = w >> 1, wc = w & 1;                                         \
  const int sr = lane >> 2, sc = (lane & 3) * 8;                             \
  const int arow = wr * 64 + (lane & 15);                                    \
  const int brow = wc * 64 + (lane & 15);                                    \
  const int kk = (lane >> 4) * 8;                                            \
  unsigned short* lA = &As[0][(w * 32) * 32];                                \
  unsigned short* lB = &Bs[0][(w * 32) * 32];

// Wo projection + bias + residual -> qres (f32); grid (8,32) = 256 blocks
__global__ __launch_bounds__(256) void gemm_wo(
    const unsigned short* __restrict__ A, const unsigned short* __restrict__ Bt,
    float* __restrict__ outf, const float* __restrict__ bias,
    const float* __restrict__ addm) {
  const int K = 1024, N = 1024;
  GEMM_PREAMBLE
  int bx, by;
  xcd_swizzle(bx, by);
  const int row0 = by * 128, col0 = bx * 128;
  const unsigned short* gA0 = A + (size_t)(row0 + w * 32 + sr) * K + sc;
  const unsigned short* gA1 = gA0 + (size_t)16 * K;
  const unsigned short* gB = Bt + (size_t)(col0 + w * 32 + sr) * K + sc;
  f32x4 acc[4][4] = {};
  GEMM_LOOP(1024)
#pragma unroll
  for (int m = 0; m < 4; ++m) {
    const int rbase = row0 + wr * 64 + m * 16 + (lane >> 4) * 4;
#pragma unroll
    for (int n = 0; n < 4; ++n) {
      const int c = col0 + wc * 64 + n * 16 + (lane & 15);
#pragma unroll
      for (int r = 0; r < 4; ++r) {
        const size_t idx = (size_t)(rbase + r) * N + c;
        outf[idx] = acc[m][n][r] + bias[c] + addm[idx];
      }
    }
  }
}

// ========== Core B: 128x256 tile, BK=32, 512 thr (8 waves 2Mx4N), dbuf ==========
// Same sync structure as Core A; scaled geometry for K-amortization at short K.
// A tile [128][32] = 8KB/buf (1 stage pass); B tile [256][32] = 16KB/buf (2 passes).
#define G2_PREAMBLE                                                          \
  __shared__ __align__(16) unsigned short As[2][128 * 32];                   \
  __shared__ __align__(16) unsigned short Bs[2][256 * 32];                   \
  const int tid = threadIdx.x;                                               \
  const int lane = tid & 63, w = tid >> 6;                                   \
  const int wr = w >> 2, wc = w & 3;                                         \
  const int arow = wr * 64 + (lane & 15);                                    \
  const int brow = wc * 64 + (lane & 15);                                    \
  const int kk = (lane >> 4) * 8;                                            \
  char* lA = (char*)&As[0][0] + w * 1024;                                    \
  char* lB = (char*)&Bs[0][0] + w * 1024;

#define G2_STAGE(buf, k0)                                                    \
  gload16(gA + (k0), lA + (buf) * 8192);                                     \
  gload16(gB0 + (k0), lB + (buf) * 16384);                                   \
  gload16(gB1 + (k0), lB + (buf) * 16384 + 8192);

#define G2_COMPUTE(buf)                                                      \
  {                                                                          \
    const unsigned short* sA = &As[buf][0];                                  \
    const unsigned short* sB = &Bs[buf][0];                                  \
    short8 af[4], bfr[4];                                                    \
    _Pragma("unroll") for (int m = 0; m < 4; ++m)                            \
        af[m] = *(const short8*)&sA[(arow + m * 16) * 32 + kk];              \
    _Pragma("unroll") for (int n = 0; n < 4; ++n)                            \
        bfr[n] = *(const short8*)&sB[(brow + n * 16) * 32 + kk];             \
    _Pragma("unroll") for (int m = 0; m < 4; ++m)                            \
      _Pragma("unroll") for (int n = 0; n < 4; ++n)                          \
        acc[m][n] = __builtin_amdgcn_mfma_f32_16x16x32_bf16(                 \
            af[m], bfr[n], acc[m][n], 0, 0, 0);                              \
  }

#define G2_LOOP(KD)                                                          \
  G2_STAGE(0, 0)                                                             \
  __syncthreads();                                                           \
  for (int k0 = 0; k0 < (KD); k0 += 64) {                                    \
    G2_STAGE(1, k0 + 32)                                                     \
    G2_COMPUTE(0)                                                            \
    __syncthreads();                                                         \
    if (k0 + 64 < (KD)) { G2_STAGE(0, k0 + 64) }                             \
    G2_COMPUTE(1)                                                            \
    __syncthreads();                                                         \
  }

// fused q/k/v projection: blockIdx.z selects which; grid (4, 32, 3)
__global__ __launch_bounds__(512) void gemm_qkv(
    const unsigned short* __restrict__ lnq, const unsigned short* __restrict__ lnk,
    const unsigned short* __restrict__ lnv, const unsigned short* __restrict__ WqT,
    const unsigned short* __restrict__ WkT, const unsigned short* __restrict__ WvT,
    unsigned short* __restrict__ qf, unsigned short* __restrict__ kf,
    unsigned short* __restrict__ vh) {
  const int z = blockIdx.z;
  const unsigned short* A = z == 0 ? lnq : z == 1 ? lnk : lnv;
  const unsigned short* Bt = z == 0 ? WqT : z == 1 ? WkT : WvT;
  unsigned short* outb = z == 0 ? qf : z == 1 ? kf : vh;
  const int K = 1024, N = 1024;
  G2_PREAMBLE
  int bx, by;
  xcd_swizzle(bx, by);
  const int row0 = by * 128, col0 = bx * 256;
  const unsigned short* gA = A + (size_t)(row0 + (tid >> 2)) * K + (tid & 3) * 8;
  const unsigned short* gB0 = Bt + (size_t)(col0 + (tid >> 2)) * K + (tid & 3) * 8;
  const unsigned short* gB1 = Bt + (size_t)(col0 + 128 + (tid >> 2)) * K + (tid & 3) * 8;
  f32x4 acc[4][4] = {};
  G2_LOOP(1024)
#pragma unroll
  for (int m = 0; m < 4; ++m) {
    const int rbase = row0 + wr * 64 + m * 16 + (lane >> 4) * 4;
#pragma unroll
    for (int n = 0; n < 4; ++n) {
      const int c = col0 + wc * 64 + n * 16 + (lane & 15);
#pragma unroll
      for (int r = 0; r < 4; ++r) {
        float v = acc[m][n][r];
        if (z < 2) v = v > 0.f ? v + 1.f : __expf(v);  // elu+1
        outb[(size_t)(rbase + r) * N + c] = f2bf(v);
      }
    }
  }
}

// gathered MoE GEMM on Core B; PHASE1 grid (8,72), PHASE2 grid (4,72)
template <int PHASE>
__global__ __launch_bounds__(512) void gemm_moe(
    const unsigned short* __restrict__ Asrc, const unsigned short* __restrict__ Ball,
    const float* __restrict__ bias_all,
    const int* __restrict__ seg, const int* __restrict__ tok,
    const float* __restrict__ wgt, const int* __restrict__ slt,
    unsigned short* __restrict__ Hb, unsigned short* __restrict__ eoSb) {
  constexpr int K = (PHASE == 1) ? 1024 : 2048;
  constexpr int N = (PHASE == 1) ? 2048 : 1024;
  G2_PREAMBLE
  int bx, by;
  xcd_swizzle(bx, by);
  const int row0 = by * 128;
  if (row0 >= seg[8]) return;
  int e = 0;
  while (e < 7 && row0 >= seg[e + 1]) ++e;
  const int col0 = bx * 256;
  const unsigned short* Bt = Ball + (size_t)e * N * K;
  const unsigned short* gA;
  if constexpr (PHASE == 1) {
    const int t0 = tok[row0 + (tid >> 2)];
    gA = Asrc + (size_t)(t0 < 0 ? 0 : t0) * K + (tid & 3) * 8;
  } else {
    gA = Asrc + (size_t)(row0 + (tid >> 2)) * K + (tid & 3) * 8;
  }
  const unsigned short* gB0 = Bt + (size_t)(col0 + (tid >> 2)) * K + (tid & 3) * 8;
  const unsigned short* gB1 = Bt + (size_t)(col0 + 128 + (tid >> 2)) * K + (tid & 3) * 8;
  f32x4 acc[4][4] = {};
  if constexpr (PHASE == 1) { G2_LOOP(1024) }
  else { G2_LOOP(2048) }
  const float* bias = bias_all + (size_t)e * N;
#pragma unroll
  for (int m = 0; m < 4; ++m) {
    const int rloc = wr * 64 + m * 16 + (lane >> 4) * 4;
#pragma unroll
    for (int n = 0; n < 4; ++n) {
      const int c = col0 + wc * 64 + n * 16 + (lane & 15);
#pragma unroll
      for (int r = 0; r < 4; ++r) {
        const int gr = row0 + rloc + r;
        float v = acc[m][n][r] + bias[c];
        if constexpr (PHASE == 1) {
          v = 0.5f * v * (1.f + erff(v * 0.70710678118654752f));
          Hb[(size_t)gr * 2048 + c] = f2bf(v);
        } else {
          const int tkn = tok[gr];
          if (tkn >= 0)
            eoSb[(size_t)slt[gr] * (4096 * 1024) + (size_t)tkn * 1024 + c] =
                f2bf(wgt[gr] * v);
        }
      }
    }
  }
}

// ---------------- attention: kv partials ----------------
__global__ __launch_bounds__(256) void kvpart_kernel(
    const unsigned short* __restrict__ kf, const unsigned short* __restrict__ vh,
    float* __restrict__ kvp, float* __restrict__ ksp) {
  const int bh = blockIdx.x;
  const int b = bh >> 3, h = bh & 7;
  const int ch = blockIdx.y;
  const int tid = threadIdx.x;
  const int d0 = (tid >> 4) * 8, e0 = (tid & 15) * 8;
  __shared__ unsigned short kb[64][128];
  __shared__ unsigned short vb[64][128];
  for (int i = tid; i < 1024; i += 256) {
    const int tt = i >> 4, dd = (i & 15) * 8;
    const size_t base = ((size_t)((b * 1024 + ch * 64 + tt) * 8 + h)) * 128 + dd;
    *(short8*)&kb[tt][dd] = *(const short8*)&kf[base];
    *(short8*)&vb[tt][dd] = *(const short8*)&vh[base];
  }
  __syncthreads();
  float acc[8][8] = {};
  float ks[8] = {};
  for (int tt = 0; tt < 64; ++tt) {
    float kv8[8], vv8[8];
    const short8 kr = *(const short8*)&kb[tt][d0];
    const short8 vr = *(const short8*)&vb[tt][e0];
#pragma unroll
    for (int j = 0; j < 8; ++j) {
      kv8[j] = bf2f((unsigned short)kr[j]);
      vv8[j] = bf2f((unsigned short)vr[j]);
    }
#pragma unroll
    for (int i = 0; i < 8; ++i)
#pragma unroll
      for (int j = 0; j < 8; ++j) acc[i][j] += kv8[i] * vv8[j];
    if ((tid & 15) == 0)
#pragma unroll
      for (int i = 0; i < 8; ++i) ks[i] += kv8[i];
  }
  const size_t obase = ((size_t)(ch * 32 + bh) * 128) * 128;
#pragma unroll
  for (int i = 0; i < 8; ++i)
#pragma unroll
    for (int j = 0; j < 8; ++j)
      kvp[obase + (size_t)(d0 + i) * 128 + e0 + j] = acc[i][j];
  if ((tid & 15) == 0)
#pragma unroll
    for (int i = 0; i < 8; ++i) ksp[(size_t)(ch * 32 + bh) * 128 + d0 + i] = ks[i];
}

__global__ __launch_bounds__(256) void kvreduce_kernel(
    const float* __restrict__ kvp, const float* __restrict__ ksp,
    unsigned short* __restrict__ kvb, float* __restrict__ ksum) {
  const int idx = blockIdx.x * 256 + threadIdx.x;
  const int CS = 32 * 128 * 128;
  float s = 0.f;
#pragma unroll
  for (int c = 0; c < 16; ++c) s += kvp[(size_t)c * CS + idx];
  kvb[idx] = f2bf(s);
  if (idx < 32 * 128) {
    float t = 1e-6f;
#pragma unroll
    for (int c = 0; c < 16; ++c) t += ksp[c * 4096 + idx];
    ksum[idx] = t;
  }
}

__global__ __launch_bounds__(256) void attnout_kernel(
    const unsigned short* __restrict__ qf, const unsigned short* __restrict__ kvb,
    const float* __restrict__ ksum, unsigned short* __restrict__ ctx) {
  const int bh = blockIdx.x, b = bh >> 3, h = bh & 7;
  const int tb = blockIdx.y;
  const int tid = threadIdx.x;
  __shared__ unsigned short kvl[128 * 128];
  __shared__ float ksl[128];
  __shared__ float denom[128];
  __shared__ unsigned short qfl[128 * 32];
  for (int i = tid; i < 16384; i += 256) kvl[i] = kvb[(size_t)bh * 16384 + i];
  if (tid < 128) ksl[tid] = ksum[bh * 128 + tid];
  __syncthreads();
  if (tid < 128) {
    const int t = tb * 128 + tid;
    const size_t qbase = ((size_t)((b * 1024 + t) * 8 + h)) * 128;
    float s = 0.f;
    for (int d = 0; d < 128; ++d) s += bf2f(qf[qbase + d]) * ksl[d];
    denom[tid] = s;
  }
  float acc[8][8] = {};
  const int t0 = (tid >> 4) * 8, e0 = (tid & 15) * 8;
  for (int dc = 0; dc < 128; dc += 32) {
    __syncthreads();
    for (int i = tid; i < 128 * 32; i += 256) {
      const int tt = i >> 5, dd = i & 31;
      qfl[i] = qf[((size_t)((b * 1024 + tb * 128 + tt) * 8 + h)) * 128 + dc + dd];
    }
    __syncthreads();
    for (int dd = 0; dd < 32; ++dd) {
      float kvrow[8];
#pragma unroll
      for (int j = 0; j < 8; ++j) kvrow[j] = bf2f(kvl[(dc + dd) * 128 + e0 + j]);
#pragma unroll
      for (int i = 0; i < 8; ++i) {
        const float qv = bf2f(qfl[(t0 + i) * 32 + dd]);
#pragma unroll
        for (int j = 0; j < 8; ++j) acc[i][j] += qv * kvrow[j];
      }
    }
  }
  __syncthreads();
#pragma unroll
  for (int i = 0; i < 8; ++i) {
    const int t = tb * 128 + t0 + i;
    const float inv = 1.f / denom[t0 + i];
#pragma unroll
    for (int j = 0; j < 8; ++j)
      ctx[((size_t)(b * 1024 + t)) * 1024 + h * 128 + e0 + j] = f2bf(acc[i][j] * inv);
  }
}

__global__ void setptr_kernel(const float* Wq, const float* Wk, const float* Wv,
                              const float* Wo, unsigned short* WqT, unsigned short* WkT,
                              unsigned short* WvT, unsigned short* WoT,
                              const float** ins, unsigned short** outs) {
  if (threadIdx.x == 0) {
    ins[0] = Wq; ins[1] = Wk; ins[2] = Wv; ins[3] = Wo;
    outs[0] = WqT; outs[1] = WkT; outs[2] = WvT; outs[3] = WoT;
  }
}

// ---------------- host launcher ----------------
extern "C" void kernel_launch(void* const* d_in, const int* in_sizes, int n_in,
                              void* d_out, int out_size, void* d_ws, size_t ws_size,
                              hipStream_t stream) {
  (void)in_sizes; (void)n_in; (void)out_size; (void)ws_size;
  const float* vin  = (const float*)d_in[0];
  const float* kin  = (const float*)d_in[1];
  const float* qin  = (const float*)d_in[2];
  const float* noise = (const float*)d_in[3];
  const float* g_v = (const float*)d_in[4];  const float* b_v = (const float*)d_in[5];
  const float* g_k = (const float*)d_in[6];  const float* b_k = (const float*)d_in[7];
  const float* g_q = (const float*)d_in[8];  const float* b_q = (const float*)d_in[9];
  const float* g_moe = (const float*)d_in[10]; const float* b_moe = (const float*)d_in[11];
  const float* g_out = (const float*)d_in[12]; const float* b_out = (const float*)d_in[13];
  const float* Wq = (const float*)d_in[14];
  const float* Wk = (const float*)d_in[15];
  const float* Wv = (const float*)d_in[16];
  const float* Wo = (const float*)d_in[17];
  const float* bo = (const float*)d_in[18];
  const float* Wr = (const float*)d_in[19];
  const float* br = (const float*)d_in[20];
  const float* W1 = (const float*)d_in[21];
  const float* b1 = (const float*)d_in[22];
  const float* W2 = (const float*)d_in[23];
  const float* b2 = (const float*)d_in[24];
  float* out = (float*)d_out;

  const int NT = 4096, D = 1024, FF = 2048;
  const int MAXR = 9216;  // 8192 pairs + per-expert pad to 128

  char* p = (char*)d_ws;
  auto alloc = [&](size_t bytes) {
    void* r = (void*)p;
    p += (bytes + 255) & ~(size_t)255;
    return r;
  };
  char* base0 = p;
  unsigned short* lnq = (unsigned short*)alloc((size_t)NT * D * 2);
  unsigned short* lnk = (unsigned short*)alloc((size_t)NT * D * 2);
  unsigned short* lnv = (unsigned short*)alloc((size_t)NT * D * 2);
  unsigned short* WqT = (unsigned short*)alloc((size_t)D * D * 2);
  unsigned short* WkT = (unsigned short*)alloc((size_t)D * D * 2);
  unsigned short* WvT = (unsigned short*)alloc((size_t)D * D * 2);
  unsigned short* WoT = (unsigned short*)alloc((size_t)D * D * 2);
  unsigned short* qf  = (unsigned short*)alloc((size_t)NT * D * 2);
  unsigned short* kf  = (unsigned short*)alloc((size_t)NT * D * 2);
  unsigned short* vh  = (unsigned short*)alloc((size_t)NT * D * 2);
  unsigned short* kvb = (unsigned short*)alloc((size_t)32 * 128 * 128 * 2);
  float* ksp  = (float*)alloc((size_t)16 * 32 * 128 * 4);
  float* ksum = (float*)alloc((size_t)32 * 128 * 4);
  unsigned short* ctx = (unsigned short*)alloc((size_t)NT * D * 2);
  float* qres = (float*)alloc((size_t)NT * D * 4);
  float* xf   = (float*)alloc((size_t)NT * D * 4);
  unsigned short* xb = (unsigned short*)alloc((size_t)NT * D * 2);
  unsigned short* W1T_all = (unsigned short*)alloc((size_t)8 * D * FF * 2);
  unsigned short* W2T_all = (unsigned short*)alloc((size_t)8 * FF * D * 2);
  float* kvp = (float*)alloc((size_t)16 * 32 * 128 * 128 * 4);  // 32MB
  unsigned short* eoSb = (unsigned short*)alloc((size_t)2 * NT * D * 2);  // bf16 slots
  int* pick = (int*)alloc((size_t)NT * 2 * 4);
  float* pw = (float*)alloc((size_t)NT * 2 * 4);
  int* seg = (int*)alloc(9 * 4);
  int* tokl = (int*)alloc(MAXR * 4);
  float* wgt = (float*)alloc(MAXR * 4);
  int* slt = (int*)alloc(MAXR * 4);
  const float** tins = (const float**)alloc(4 * sizeof(void*));
  unsigned short** touts = (unsigned short**)alloc(4 * sizeof(void*));
  unsigned short* Hb = (unsigned short*)base0;  // 36MB alias over dead early bufs

  // 1) weight transposes (batched z=4)
  setptr_kernel<<<dim3(1), 64, 0, stream>>>(Wq, Wk, Wv, Wo, WqT, WkT, WvT, WoT,
                                            tins, touts);
  transposeB_kernel<<<dim3(32, 32, 4), 256, 0, stream>>>(tins, touts, D, D);

  // 2) LN(q,k,v)
  ln3_kernel<<<dim3(NT, 3), 256, 0, stream>>>(qin, kin, vin, g_q, b_q, g_k, b_k, g_v, b_v,
                                              lnq, lnk, lnv);

  // 3) fused q/k/v projections (128x256 tiles, 512 thr)
  gemm_qkv<<<dim3(D / 256, NT / 128, 3), 512, 0, stream>>>(lnq, lnk, lnv, WqT, WkT, WvT,
                                                           qf, kf, vh);

  // 4) linear attention state
  kvpart_kernel<<<dim3(32, 16), 256, 0, stream>>>(kf, vh, kvp, ksp);
  kvreduce_kernel<<<dim3(2048), 256, 0, stream>>>(kvp, ksp, kvb, ksum);
  attnout_kernel<<<dim3(32, 8), 256, 0, stream>>>(qf, kvb, ksum, ctx);

  // 5) out projection + bias + residual q -> q_res (128x128 core)
  gemm_wo<<<dim3(D / 128, NT / 128), 256, 0, stream>>>(ctx, WoT, qres, bo, qin);

  // 6) fused MoE pre-LN/router + single-block routing build
  ln_moe_router_kernel<<<dim3(NT), 256, 0, stream>>>(qres, g_moe, b_moe, Wr, br, noise,
                                                     xf, xb, pick, pw);
  route_build_kernel<<<dim3(1), 1024, 0, stream>>>(pick, pw, seg, tokl, wgt, slt);

  // 7) expert weight transposes (batched)
  transpose8_kernel<<<dim3(FF / 32, D / 32, 8), 256, 0, stream>>>(W1, W1T_all, D, FF);
  transpose8_kernel<<<dim3(D / 32, FF / 32, 8), 256, 0, stream>>>(W2, W2T_all, FF, D);

  // 8) gathered expert GEMMs (128x256 tiles, 512 thr)
  gemm_moe<1><<<dim3(FF / 256, MAXR / 128), 512, 0, stream>>>(
      xb, W1T_all, b1, seg, tokl, wgt, slt, Hb, nullptr);
  gemm_moe<2><<<dim3(D / 256, MAXR / 128), 512, 0, stream>>>(
      Hb, W2T_all, b2, seg, tokl, wgt, slt, nullptr, eoSb);

  // 9) final residual LN
  final_kernel<<<dim3(NT), 256, 0, stream>>>(eoSb, xf, qres, g_out, b_out, out);
}

// Round 10
// 377.762 us; speedup vs baseline: 1.0647x; 1.0647x over previous
//
#include <hip/hip_runtime.h>
#include <math.h>

typedef __attribute__((ext_vector_type(8))) short short8;
typedef __attribute__((ext_vector_type(4))) float f32x4;

#define LN_EPS 1e-5f

__device__ __forceinline__ float bf2f(unsigned short u) {
  unsigned int x = ((unsigned int)u) << 16;
  float f;
  __builtin_memcpy(&f, &x, 4);
  return f;
}
__device__ __forceinline__ unsigned short f2bf(float f) {
  unsigned int x;
  __builtin_memcpy(&x, &f, 4);
  x += 0x7fffu + ((x >> 16) & 1u);
  return (unsigned short)(x >> 16);
}

__device__ __forceinline__ void gload16(const void* g, void* l) {
  __builtin_amdgcn_global_load_lds(
      (__attribute__((address_space(1))) void*)(void*)g,
      (__attribute__((address_space(3))) void*)l, 16, 0, 0);
}

// bijective chunked XCD swizzle (requires nx*ny % 8 == 0)
__device__ __forceinline__ void xcd_swizzle(int& bx, int& by) {
  const int nx = gridDim.x;
  const int nwg = nx * gridDim.y;
  const int orig = blockIdx.y * nx + blockIdx.x;
  const int cpx = nwg >> 3;
  const int lid = (orig & 7) * cpx + (orig >> 3);
  bx = lid % nx;
  by = lid / nx;
}

// ---------------- block reduce (sum, sumsq) over 256 threads ----------------
__device__ __forceinline__ void blockReduce2(float& a, float& b, float* s8) {
#pragma unroll
  for (int off = 32; off > 0; off >>= 1) {
    a += __shfl_down(a, off);
    b += __shfl_down(b, off);
  }
  const int w = threadIdx.x >> 6;
  if ((threadIdx.x & 63) == 0) { s8[w] = a; s8[4 + w] = b; }
  __syncthreads();
  a = s8[0] + s8[1] + s8[2] + s8[3];
  b = s8[4] + s8[5] + s8[6] + s8[7];
}

// ---------------- LN of q,k,v -> bf16 ----------------
__global__ __launch_bounds__(256) void ln3_kernel(
    const float* __restrict__ q, const float* __restrict__ k, const float* __restrict__ v,
    const float* __restrict__ gq, const float* __restrict__ bq,
    const float* __restrict__ gk, const float* __restrict__ bk,
    const float* __restrict__ gv, const float* __restrict__ bv,
    unsigned short* __restrict__ oq, unsigned short* __restrict__ ok,
    unsigned short* __restrict__ ov) {
  __shared__ float s8[8];
  const int row = blockIdx.x, which = blockIdx.y;
  const float* x = which == 0 ? q : which == 1 ? k : v;
  const float* g = which == 0 ? gq : which == 1 ? gk : gv;
  const float* b = which == 0 ? bq : which == 1 ? bk : bv;
  unsigned short* o = which == 0 ? oq : which == 1 ? ok : ov;
  const float4 xv = ((const float4*)(x + (size_t)row * 1024))[threadIdx.x];
  float s = xv.x + xv.y + xv.z + xv.w;
  float s2 = xv.x * xv.x + xv.y * xv.y + xv.z * xv.z + xv.w * xv.w;
  blockReduce2(s, s2, s8);
  const float mu = s * (1.f / 1024.f);
  const float rs = rsqrtf(s2 * (1.f / 1024.f) - mu * mu + LN_EPS);
  const int c = threadIdx.x * 4;
  const float y[4] = {xv.x, xv.y, xv.z, xv.w};
#pragma unroll
  for (int j = 0; j < 4; ++j)
    o[(size_t)row * 1024 + c + j] = f2bf((y[j] - mu) * rs * g[c + j] + b[c + j]);
}

// ------- fused: LN(q_res) -> xf,xb AND router logits/softmax/top2 (NO atomics) -------
__global__ __launch_bounds__(256) void ln_moe_router_kernel(
    const float* __restrict__ qres, const float* __restrict__ g, const float* __restrict__ b,
    const float* __restrict__ Wr, const float* __restrict__ br,
    const float* __restrict__ noise,
    float* __restrict__ xf, unsigned short* __restrict__ xb,
    int* __restrict__ pick, float* __restrict__ pw) {
  __shared__ float s8[8];
  __shared__ float sacc[32];
  const int row = blockIdx.x;
  const float4 xv = ((const float4*)(qres + (size_t)row * 1024))[threadIdx.x];
  float s = xv.x + xv.y + xv.z + xv.w;
  float s2 = xv.x * xv.x + xv.y * xv.y + xv.z * xv.z + xv.w * xv.w;
  blockReduce2(s, s2, s8);
  const float mu = s * (1.f / 1024.f);
  const float rs = rsqrtf(s2 * (1.f / 1024.f) - mu * mu + LN_EPS);
  const int c = threadIdx.x * 4;
  const float yin[4] = {xv.x, xv.y, xv.z, xv.w};
  float y[4];
#pragma unroll
  for (int j = 0; j < 4; ++j) {
    y[j] = (yin[j] - mu) * rs * g[c + j] + b[c + j];
    xf[(size_t)row * 1024 + c + j] = y[j];
    xb[(size_t)row * 1024 + c + j] = f2bf(y[j]);
  }
  float acc[8] = {};
  const float4* wrv = (const float4*)(Wr + (size_t)c * 8);
#pragma unroll
  for (int j = 0; j < 4; ++j) {
    const float4 w0 = wrv[j * 2], w1 = wrv[j * 2 + 1];
    acc[0] += y[j] * w0.x; acc[1] += y[j] * w0.y;
    acc[2] += y[j] * w0.z; acc[3] += y[j] * w0.w;
    acc[4] += y[j] * w1.x; acc[5] += y[j] * w1.y;
    acc[6] += y[j] * w1.z; acc[7] += y[j] * w1.w;
  }
#pragma unroll
  for (int off = 32; off > 0; off >>= 1)
#pragma unroll
    for (int e = 0; e < 8; ++e) acc[e] += __shfl_down(acc[e], off);
  const int w = threadIdx.x >> 6;
  if ((threadIdx.x & 63) == 0)
#pragma unroll
    for (int e = 0; e < 8; ++e) sacc[w * 8 + e] = acc[e];
  __syncthreads();
  if (threadIdx.x == 0) {
    float lg[8], mx = -1e30f;
#pragma unroll
    for (int e = 0; e < 8; ++e) {
      lg[e] = sacc[e] + sacc[8 + e] + sacc[16 + e] + sacc[24 + e] + br[e] +
              0.1f * noise[(size_t)row * 8 + e];
      mx = fmaxf(mx, lg[e]);
    }
    float ssum = 0.f;
#pragma unroll
    for (int e = 0; e < 8; ++e) { lg[e] = expf(lg[e] - mx); ssum += lg[e]; }
    const float inv = 1.f / ssum;
#pragma unroll
    for (int e = 0; e < 8; ++e) lg[e] *= inv;
    int i1 = -1, i2 = -1;
    float m1 = -1.f, m2 = -1.f;
#pragma unroll
    for (int e = 0; e < 8; ++e) {
      if (lg[e] > m1) { m2 = m1; i2 = i1; m1 = lg[e]; i1 = e; }
      else if (lg[e] > m2) { m2 = lg[e]; i2 = e; }
    }
    pick[row * 2] = i1; pick[row * 2 + 1] = i2;
    pw[row * 2] = m1;  pw[row * 2 + 1] = m2;
  }
}

// ------- single-block routing build (LDS atomics only), pad-to-128 -------
__global__ __launch_bounds__(1024) void route_build_kernel(
    const int* __restrict__ pick, const float* __restrict__ pw,
    int* __restrict__ seg, int* __restrict__ tok, float* __restrict__ wgt,
    int* __restrict__ slt) {
  __shared__ int cnt[8];
  __shared__ int segs[9];
  __shared__ int cur[8];
  const int tid = threadIdx.x;
  if (tid < 8) { cnt[tid] = 0; cur[tid] = 0; }
  __syncthreads();
  for (int i = tid; i < 8192; i += 1024) atomicAdd(&cnt[pick[i]], 1);
  __syncthreads();
  if (tid == 0) {
    int o = 0;
    for (int e = 0; e < 8; ++e) { segs[e] = o; o += (cnt[e] + 127) & ~127; }
    segs[8] = o;
  }
  __syncthreads();
  for (int i = tid; i < 9216; i += 1024) tok[i] = -1;
  if (tid < 9) seg[tid] = segs[tid];
  __syncthreads();
  for (int i = tid; i < 8192; i += 1024) {
    const int n = i >> 1, sl = i & 1;
    const int e = pick[i];
    const int p = atomicAdd(&cur[e], 1);
    const int gr = segs[e] + p;
    tok[gr] = n;
    wgt[gr] = pw[i];
    slt[gr] = sl;
  }
}

// ------- final: out = qres + LN(eo0 + eo1 + x); expert slots in bf16 -------
__global__ __launch_bounds__(256) void final_kernel(
    const unsigned short* __restrict__ eoSb, const float* __restrict__ xf,
    const float* __restrict__ qres, const float* __restrict__ g,
    const float* __restrict__ b, float* __restrict__ out) {
  __shared__ float s8[8];
  const int row = blockIdx.x;
  const size_t SLOT = (size_t)4096 * 1024;
  const unsigned short* p0 = eoSb + (size_t)row * 1024 + threadIdx.x * 4;
  const unsigned short* p1 = eoSb + SLOT + (size_t)row * 1024 + threadIdx.x * 4;
  const float4 xv = ((const float4*)(xf + (size_t)row * 1024))[threadIdx.x];
  float y[4];
#pragma unroll
  for (int j = 0; j < 4; ++j) y[j] = bf2f(p0[j]) + bf2f(p1[j]);
  y[0] += xv.x; y[1] += xv.y; y[2] += xv.z; y[3] += xv.w;
  float s = y[0] + y[1] + y[2] + y[3];
  float s2 = y[0] * y[0] + y[1] * y[1] + y[2] * y[2] + y[3] * y[3];
  blockReduce2(s, s2, s8);
  const float mu = s * (1.f / 1024.f);
  const float rs = rsqrtf(s2 * (1.f / 1024.f) - mu * mu + LN_EPS);
  const int c = threadIdx.x * 4;
#pragma unroll
  for (int j = 0; j < 4; ++j) {
    const size_t idx = (size_t)row * 1024 + c + j;
    out[idx] = qres[idx] + (y[j] - mu) * rs * g[c + j] + b[c + j];
  }
}

// ------- batched transpose + f32->bf16 -------
__global__ __launch_bounds__(256) void transposeB_kernel(
    const float* const* __restrict__ ins, unsigned short* const* __restrict__ outs,
    int R, int C) {
  __shared__ float t[32][33];
  const float* inz = ins[blockIdx.z];
  unsigned short* outz = outs[blockIdx.z];
  const int bx = blockIdx.x, by = blockIdx.y;
  const int tx = threadIdx.x & 31, ty = threadIdx.x >> 5;
#pragma unroll
  for (int i = 0; i < 32; i += 8)
    t[ty + i][tx] = inz[(size_t)(by * 32 + ty + i) * C + bx * 32 + tx];
  __syncthreads();
#pragma unroll
  for (int i = 0; i < 32; i += 8)
    outz[(size_t)(bx * 32 + ty + i) * R + by * 32 + tx] = f2bf(t[tx][ty + i]);
}

__global__ __launch_bounds__(256) void transpose8_kernel(
    const float* __restrict__ in, unsigned short* __restrict__ out, int R, int C) {
  __shared__ float t[32][33];
  const float* inz = in + (size_t)blockIdx.z * R * C;
  unsigned short* outz = out + (size_t)blockIdx.z * R * C;
  const int bx = blockIdx.x, by = blockIdx.y;
  const int tx = threadIdx.x & 31, ty = threadIdx.x >> 5;
#pragma unroll
  for (int i = 0; i < 32; i += 8)
    t[ty + i][tx] = inz[(size_t)(by * 32 + ty + i) * C + bx * 32 + tx];
  __syncthreads();
#pragma unroll
  for (int i = 0; i < 32; i += 8)
    outz[(size_t)(bx * 32 + ty + i) * R + by * 32 + tx] = f2bf(t[tx][ty + i]);
}

// ========== Core A: 128x128 tile, BK=32, 256 thr, dbuf + chunk-XOR swizzle ==========
// LDS rows are 64B (4 x 16B chunks). f(row) = (row>>1)&3 XORs the chunk index:
// stage source chunk = (lane&3)^f(destrow)  [gload_lds dest stays linear],
// read chunk = (lane>>4)^f(row)  -> 2-way bank aliasing (free) instead of 8-way.
#define GEMM_STAGE(buf, k0, KD)                                              \
  gload16(gA0 + (k0), lA + (buf) * 4096);                                    \
  gload16(gA1 + (k0), lA + (buf) * 4096 + 16 * 32);                          \
  gload16(gB + (k0), lB + (buf) * 4096);                                     \
  gload16(gB + (size_t)16 * (KD) + (k0), lB + (buf) * 4096 + 16 * 32);

#define GEMM_COMPUTE(buf)                                                    \
  {                                                                          \
    const unsigned short* sA = &As[buf][0];                                  \
    const unsigned short* sB = &Bs[buf][0];                                  \
    short8 af[4], bfr[4];                                                    \
    _Pragma("unroll") for (int m = 0; m < 4; ++m)                            \
        af[m] = *(const short8*)&sA[(arow + m * 16) * 32 + kksw];            \
    _Pragma("unroll") for (int n = 0; n < 4; ++n)                            \
        bfr[n] = *(const short8*)&sB[(brow + n * 16) * 32 + kksw];           \
    _Pragma("unroll") for (int m = 0; m < 4; ++m)                            \
      _Pragma("unroll") for (int n = 0; n < 4; ++n)                          \
        acc[m][n] = __builtin_amdgcn_mfma_f32_16x16x32_bf16(                 \
            af[m], bfr[n], acc[m][n], 0, 0, 0);                              \
  }

#define GEMM_LOOP(KD)                                                        \
  GEMM_STAGE(0, 0, KD)                                                       \
  __syncthreads();                                                           \
  for (int k0 = 0; k0 < (KD); k0 += 64) {                                    \
    GEMM_STAGE(1, k0 + 32, KD)                                               \
    GEMM_COMPUTE(0)                                                          \
    __syncthreads();                                                         \
    if (k0 + 64 < (KD)) { GEMM_STAGE(0, k0 + 64, KD) }                       \
    GEMM_COMPUTE(1)                                                          \
    __syncthreads();                                                         \
  }

#define GEMM_PREAMBLE                                                        \
  __shared__ __align__(16) unsigned short As[2][128 * 32];                   \
  __shared__ __align__(16) unsigned short Bs[2][128 * 32];                   \
  const int tid = threadIdx.x;                                               \
  const int lane = tid & 63, w = tid >> 6;                                   \
  const int wr = w >> 1, wc = w & 1;                                         \
  const int sr = lane >> 2;                                                  \
  const int sc = (((lane & 3) ^ ((lane >> 3) & 3)) * 8); /* swizzled src */  \
  const int arow = wr * 64 + (lane & 15);                                    \
  const int brow = wc * 64 + (lane & 15);                                    \
  const int kksw = (((lane >> 4) ^ ((lane >> 1) & 3)) * 8); /* swz read */   \
  unsigned short* lA = &As[0][(w * 32) * 32];                                \
  unsigned short* lB = &Bs[0][(w * 32) * 32];

// fused q/k/v projection: blockIdx.z selects which; grid (8,32,3)
__global__ __launch_bounds__(256) void gemm_qkv(
    const unsigned short* __restrict__ lnq, const unsigned short* __restrict__ lnk,
    const unsigned short* __restrict__ lnv, const unsigned short* __restrict__ WqT,
    const unsigned short* __restrict__ WkT, const unsigned short* __restrict__ WvT,
    unsigned short* __restrict__ qf, unsigned short* __restrict__ kf,
    unsigned short* __restrict__ vh) {
  const int z = blockIdx.z;
  const unsigned short* A = z == 0 ? lnq : z == 1 ? lnk : lnv;
  const unsigned short* Bt = z == 0 ? WqT : z == 1 ? WkT : WvT;
  unsigned short* outb = z == 0 ? qf : z == 1 ? kf : vh;
  const int K = 1024, N = 1024;
  GEMM_PREAMBLE
  int bx, by;
  xcd_swizzle(bx, by);
  const int row0 = by * 128, col0 = bx * 128;
  const unsigned short* gA0 = A + (size_t)(row0 + w * 32 + sr) * K + sc;
  const unsigned short* gA1 = gA0 + (size_t)16 * K;
  const unsigned short* gB = Bt + (size_t)(col0 + w * 32 + sr) * K + sc;
  f32x4 acc[4][4] = {};
  GEMM_LOOP(1024)
#pragma unroll
  for (int m = 0; m < 4; ++m) {
    const int rbase = row0 + wr * 64 + m * 16 + (lane >> 4) * 4;
#pragma unroll
    for (int n = 0; n < 4; ++n) {
      const int c = col0 + wc * 64 + n * 16 + (lane & 15);
#pragma unroll
      for (int r = 0; r < 4; ++r) {
        float v = acc[m][n][r];
        if (z < 2) v = v > 0.f ? v + 1.f : __expf(v);  // elu+1
        outb[(size_t)(rbase + r) * N + c] = f2bf(v);
      }
    }
  }
}

// Wo projection + bias + residual -> qres (f32); grid (8,32)
__global__ __launch_bounds__(256) void gemm_wo(
    const unsigned short* __restrict__ A, const unsigned short* __restrict__ Bt,
    float* __restrict__ outf, const float* __restrict__ bias,
    const float* __restrict__ addm) {
  const int K = 1024, N = 1024;
  GEMM_PREAMBLE
  int bx, by;
  xcd_swizzle(bx, by);
  const int row0 = by * 128, col0 = bx * 128;
  const unsigned short* gA0 = A + (size_t)(row0 + w * 32 + sr) * K + sc;
  const unsigned short* gA1 = gA0 + (size_t)16 * K;
  const unsigned short* gB = Bt + (size_t)(col0 + w * 32 + sr) * K + sc;
  f32x4 acc[4][4] = {};
  GEMM_LOOP(1024)
#pragma unroll
  for (int m = 0; m < 4; ++m) {
    const int rbase = row0 + wr * 64 + m * 16 + (lane >> 4) * 4;
#pragma unroll
    for (int n = 0; n < 4; ++n) {
      const int c = col0 + wc * 64 + n * 16 + (lane & 15);
#pragma unroll
      for (int r = 0; r < 4; ++r) {
        const size_t idx = (size_t)(rbase + r) * N + c;
        outf[idx] = acc[m][n][r] + bias[c] + addm[idx];
      }
    }
  }
}

// ---------------- gathered MoE GEMM (Core A; phase-2 writes bf16 slots) ----------------
template <int PHASE>
__global__ __launch_bounds__(256) void gemm_moe(
    const unsigned short* __restrict__ Asrc, const unsigned short* __restrict__ Ball,
    const float* __restrict__ bias_all,
    const int* __restrict__ seg, const int* __restrict__ tok,
    const float* __restrict__ wgt, const int* __restrict__ slt,
    unsigned short* __restrict__ Hb, unsigned short* __restrict__ eoSb) {
  constexpr int K = (PHASE == 1) ? 1024 : 2048;
  constexpr int N = (PHASE == 1) ? 2048 : 1024;
  GEMM_PREAMBLE
  int bx, by;
  xcd_swizzle(bx, by);
  const int row0 = by * 128;
  if (row0 >= seg[8]) return;
  int e = 0;
  while (e < 7 && row0 >= seg[e + 1]) ++e;
  const int col0 = bx * 128;
  const unsigned short* Bt = Ball + (size_t)e * N * K;
  const int gr0 = row0 + w * 32 + sr;
  const int gr1 = gr0 + 16;
  const unsigned short* gA0;
  const unsigned short* gA1;
  if constexpr (PHASE == 1) {
    const int t0 = tok[gr0], t1 = tok[gr1];
    gA0 = Asrc + (size_t)(t0 < 0 ? 0 : t0) * K + sc;
    gA1 = Asrc + (size_t)(t1 < 0 ? 0 : t1) * K + sc;
  } else {
    gA0 = Asrc + (size_t)gr0 * K + sc;
    gA1 = Asrc + (size_t)gr1 * K + sc;
  }
  const unsigned short* gB = Bt + (size_t)(col0 + w * 32 + sr) * K + sc;
  f32x4 acc[4][4] = {};
  if constexpr (PHASE == 1) { GEMM_LOOP(1024) }
  else { GEMM_LOOP(2048) }
  const float* bias = bias_all + (size_t)e * N;
#pragma unroll
  for (int m = 0; m < 4; ++m) {
    const int rloc = wr * 64 + m * 16 + (lane >> 4) * 4;
#pragma unroll
    for (int n = 0; n < 4; ++n) {
      const int c = col0 + wc * 64 + n * 16 + (lane & 15);
#pragma unroll
      for (int r = 0; r < 4; ++r) {
        const int gr = row0 + rloc + r;
        float v = acc[m][n][r] + bias[c];
        if constexpr (PHASE == 1) {
          v = 0.5f * v * (1.f + erff(v * 0.70710678118654752f));
          Hb[(size_t)gr * 2048 + c] = f2bf(v);
        } else {
          const int tkn = tok[gr];
          if (tkn >= 0)
            eoSb[(size_t)slt[gr] * (4096 * 1024) + (size_t)tkn * 1024 + c] =
                f2bf(wgt[gr] * v);
        }
      }
    }
  }
}

// ---------------- attention: kv partials (bf16 partial store) ----------------
__global__ __launch_bounds__(256) void kvpart_kernel(
    const unsigned short* __restrict__ kf, const unsigned short* __restrict__ vh,
    unsigned short* __restrict__ kvp, float* __restrict__ ksp) {
  const int bh = blockIdx.x;
  const int b = bh >> 3, h = bh & 7;
  const int ch = blockIdx.y;
  const int tid = threadIdx.x;
  const int d0 = (tid >> 4) * 8, e0 = (tid & 15) * 8;
  __shared__ unsigned short kb[64][128];
  __shared__ unsigned short vb[64][128];
  for (int i = tid; i < 1024; i += 256) {
    const int tt = i >> 4, dd = (i & 15) * 8;
    const size_t base = ((size_t)((b * 1024 + ch * 64 + tt) * 8 + h)) * 128 + dd;
    *(short8*)&kb[tt][dd] = *(const short8*)&kf[base];
    *(short8*)&vb[tt][dd] = *(const short8*)&vh[base];
  }
  __syncthreads();
  float acc[8][8] = {};
  float ks[8] = {};
  for (int tt = 0; tt < 64; ++tt) {
    float kv8[8], vv8[8];
    const short8 kr = *(const short8*)&kb[tt][d0];
    const short8 vr = *(const short8*)&vb[tt][e0];
#pragma unroll
    for (int j = 0; j < 8; ++j) {
      kv8[j] = bf2f((unsigned short)kr[j]);
      vv8[j] = bf2f((unsigned short)vr[j]);
    }
#pragma unroll
    for (int i = 0; i < 8; ++i)
#pragma unroll
      for (int j = 0; j < 8; ++j) acc[i][j] += kv8[i] * vv8[j];
    if ((tid & 15) == 0)
#pragma unroll
      for (int i = 0; i < 8; ++i) ks[i] += kv8[i];
  }
  const size_t obase = ((size_t)(ch * 32 + bh) * 128) * 128;
#pragma unroll
  for (int i = 0; i < 8; ++i)
#pragma unroll
    for (int j = 0; j < 8; ++j)
      kvp[obase + (size_t)(d0 + i) * 128 + e0 + j] = f2bf(acc[i][j]);
  if ((tid & 15) == 0)
#pragma unroll
    for (int i = 0; i < 8; ++i) ksp[(size_t)(ch * 32 + bh) * 128 + d0 + i] = ks[i];
}

__global__ __launch_bounds__(256) void kvreduce_kernel(
    const unsigned short* __restrict__ kvp, const float* __restrict__ ksp,
    unsigned short* __restrict__ kvb, float* __restrict__ ksum) {
  const int idx = blockIdx.x * 256 + threadIdx.x;
  const int CS = 32 * 128 * 128;
  float s = 0.f;
#pragma unroll
  for (int c = 0; c < 16; ++c) s += bf2f(kvp[(size_t)c * CS + idx]);
  kvb[idx] = f2bf(s);
  if (idx < 32 * 128) {
    float t = 1e-6f;
#pragma unroll
    for (int c = 0; c < 16; ++c) t += ksp[c * 4096 + idx];
    ksum[idx] = t;
  }
}

__global__ __launch_bounds__(256) void attnout_kernel(
    const unsigned short* __restrict__ qf, const unsigned short* __restrict__ kvb,
    const float* __restrict__ ksum, unsigned short* __restrict__ ctx) {
  const int bh = blockIdx.x, b = bh >> 3, h = bh & 7;
  const int tb = blockIdx.y;
  const int tid = threadIdx.x;
  __shared__ unsigned short kvl[128 * 128];
  __shared__ float ksl[128];
  __shared__ float denom[128];
  __shared__ unsigned short qfl[128 * 32];
  for (int i = tid; i < 16384; i += 256) kvl[i] = kvb[(size_t)bh * 16384 + i];
  if (tid < 128) ksl[tid] = ksum[bh * 128 + tid];
  __syncthreads();
  if (tid < 128) {
    const int t = tb * 128 + tid;
    const size_t qbase = ((size_t)((b * 1024 + t) * 8 + h)) * 128;
    float s = 0.f;
    for (int d = 0; d < 128; ++d) s += bf2f(qf[qbase + d]) * ksl[d];
    denom[tid] = s;
  }
  float acc[8][8] = {};
  const int t0 = (tid >> 4) * 8, e0 = (tid & 15) * 8;
  for (int dc = 0; dc < 128; dc += 32) {
    __syncthreads();
    for (int i = tid; i < 128 * 32; i += 256) {
      const int tt = i >> 5, dd = i & 31;
      qfl[i] = qf[((size_t)((b * 1024 + tb * 128 + tt) * 8 + h)) * 128 + dc + dd];
    }
    __syncthreads();
    for (int dd = 0; dd < 32; ++dd) {
      float kvrow[8];
#pragma unroll
      for (int j = 0; j < 8; ++j) kvrow[j] = bf2f(kvl[(dc + dd) * 128 + e0 + j]);
#pragma unroll
      for (int i = 0; i < 8; ++i) {
        const float qv = bf2f(qfl[(t0 + i) * 32 + dd]);
#pragma unroll
        for (int j = 0; j < 8; ++j) acc[i][j] += qv * kvrow[j];
      }
    }
  }
  __syncthreads();
#pragma unroll
  for (int i = 0; i < 8; ++i) {
    const int t = tb * 128 + t0 + i;
    const float inv = 1.f / denom[t0 + i];
#pragma unroll
    for (int j = 0; j < 8; ++j)
      ctx[((size_t)(b * 1024 + t)) * 1024 + h * 128 + e0 + j] = f2bf(acc[i][j] * inv);
  }
}

__global__ void setptr_kernel(const float* Wq, const float* Wk, const float* Wv,
                              const float* Wo, unsigned short* WqT, unsigned short* WkT,
                              unsigned short* WvT, unsigned short* WoT,
                              const float** ins, unsigned short** outs) {
  if (threadIdx.x == 0) {
    ins[0] = Wq; ins[1] = Wk; ins[2] = Wv; ins[3] = Wo;
    outs[0] = WqT; outs[1] = WkT; outs[2] = WvT; outs[3] = WoT;
  }
}

// ---------------- host launcher ----------------
extern "C" void kernel_launch(void* const* d_in, const int* in_sizes, int n_in,
                              void* d_out, int out_size, void* d_ws, size_t ws_size,
                              hipStream_t stream) {
  (void)in_sizes; (void)n_in; (void)out_size; (void)ws_size;
  const float* vin  = (const float*)d_in[0];
  const float* kin  = (const float*)d_in[1];
  const float* qin  = (const float*)d_in[2];
  const float* noise = (const float*)d_in[3];
  const float* g_v = (const float*)d_in[4];  const float* b_v = (const float*)d_in[5];
  const float* g_k = (const float*)d_in[6];  const float* b_k = (const float*)d_in[7];
  const float* g_q = (const float*)d_in[8];  const float* b_q = (const float*)d_in[9];
  const float* g_moe = (const float*)d_in[10]; const float* b_moe = (const float*)d_in[11];
  const float* g_out = (const float*)d_in[12]; const float* b_out = (const float*)d_in[13];
  const float* Wq = (const float*)d_in[14];
  const float* Wk = (const float*)d_in[15];
  const float* Wv = (const float*)d_in[16];
  const float* Wo = (const float*)d_in[17];
  const float* bo = (const float*)d_in[18];
  const float* Wr = (const float*)d_in[19];
  const float* br = (const float*)d_in[20];
  const float* W1 = (const float*)d_in[21];
  const float* b1 = (const float*)d_in[22];
  const float* W2 = (const float*)d_in[23];
  const float* b2 = (const float*)d_in[24];
  float* out = (float*)d_out;

  const int NT = 4096, D = 1024, FF = 2048;
  const int MAXR = 9216;  // 8192 pairs + per-expert pad to 128

  char* p = (char*)d_ws;
  auto alloc = [&](size_t bytes) {
    void* r = (void*)p;
    p += (bytes + 255) & ~(size_t)255;
    return r;
  };
  char* base0 = p;
  unsigned short* lnq = (unsigned short*)alloc((size_t)NT * D * 2);
  unsigned short* lnk = (unsigned short*)alloc((size_t)NT * D * 2);
  unsigned short* lnv = (unsigned short*)alloc((size_t)NT * D * 2);
  unsigned short* WqT = (unsigned short*)alloc((size_t)D * D * 2);
  unsigned short* WkT = (unsigned short*)alloc((size_t)D * D * 2);
  unsigned short* WvT = (unsigned short*)alloc((size_t)D * D * 2);
  unsigned short* WoT = (unsigned short*)alloc((size_t)D * D * 2);
  unsigned short* qf  = (unsigned short*)alloc((size_t)NT * D * 2);
  unsigned short* kf  = (unsigned short*)alloc((size_t)NT * D * 2);
  unsigned short* vh  = (unsigned short*)alloc((size_t)NT * D * 2);
  unsigned short* kvb = (unsigned short*)alloc((size_t)32 * 128 * 128 * 2);
  float* ksp  = (float*)alloc((size_t)16 * 32 * 128 * 4);
  float* ksum = (float*)alloc((size_t)32 * 128 * 4);
  unsigned short* ctx = (unsigned short*)alloc((size_t)NT * D * 2);
  float* qres = (float*)alloc((size_t)NT * D * 4);
  float* xf   = (float*)alloc((size_t)NT * D * 4);
  unsigned short* xb = (unsigned short*)alloc((size_t)NT * D * 2);
  unsigned short* W1T_all = (unsigned short*)alloc((size_t)8 * D * FF * 2);
  unsigned short* W2T_all = (unsigned short*)alloc((size_t)8 * FF * D * 2);
  unsigned short* kvp = (unsigned short*)alloc((size_t)16 * 32 * 128 * 128 * 2);  // bf16
  unsigned short* eoSb = (unsigned short*)alloc((size_t)2 * NT * D * 2);  // bf16 slots
  int* pick = (int*)alloc((size_t)NT * 2 * 4);
  float* pw = (float*)alloc((size_t)NT * 2 * 4);
  int* seg = (int*)alloc(9 * 4);
  int* tokl = (int*)alloc(MAXR * 4);
  float* wgt = (float*)alloc(MAXR * 4);
  int* slt = (int*)alloc(MAXR * 4);
  const float** tins = (const float**)alloc(4 * sizeof(void*));
  unsigned short** touts = (unsigned short**)alloc(4 * sizeof(void*));
  unsigned short* Hb = (unsigned short*)base0;  // 36MB alias over dead early bufs

  // 1) weight transposes (batched z=4)
  setptr_kernel<<<dim3(1), 64, 0, stream>>>(Wq, Wk, Wv, Wo, WqT, WkT, WvT, WoT,
                                            tins, touts);
  transposeB_kernel<<<dim3(32, 32, 4), 256, 0, stream>>>(tins, touts, D, D);

  // 2) LN(q,k,v)
  ln3_kernel<<<dim3(NT, 3), 256, 0, stream>>>(qin, kin, vin, g_q, b_q, g_k, b_k, g_v, b_v,
                                              lnq, lnk, lnv);

  // 3) fused q/k/v projections (Core A, 768 blocks)
  gemm_qkv<<<dim3(D / 128, NT / 128, 3), 256, 0, stream>>>(lnq, lnk, lnv, WqT, WkT, WvT,
                                                           qf, kf, vh);

  // 4) linear attention state
  kvpart_kernel<<<dim3(32, 16), 256, 0, stream>>>(kf, vh, kvp, ksp);
  kvreduce_kernel<<<dim3(2048), 256, 0, stream>>>(kvp, ksp, kvb, ksum);
  attnout_kernel<<<dim3(32, 8), 256, 0, stream>>>(qf, kvb, ksum, ctx);

  // 5) out projection + bias + residual q -> q_res
  gemm_wo<<<dim3(D / 128, NT / 128), 256, 0, stream>>>(ctx, WoT, qres, bo, qin);

  // 6) fused MoE pre-LN/router + single-block routing build
  ln_moe_router_kernel<<<dim3(NT), 256, 0, stream>>>(qres, g_moe, b_moe, Wr, br, noise,
                                                     xf, xb, pick, pw);
  route_build_kernel<<<dim3(1), 1024, 0, stream>>>(pick, pw, seg, tokl, wgt, slt);

  // 7) expert weight transposes (batched)
  transpose8_kernel<<<dim3(FF / 32, D / 32, 8), 256, 0, stream>>>(W1, W1T_all, D, FF);
  transpose8_kernel<<<dim3(D / 32, FF / 32, 8), 256, 0, stream>>>(W2, W2T_all, FF, D);

  // 8) gathered expert GEMMs (Core A)
  gemm_moe<1><<<dim3(FF / 128, MAXR / 128), 256, 0, stream>>>(
      xb, W1T_all, b1, seg, tokl, wgt, slt, Hb, nullptr);
  gemm_moe<2><<<dim3(D / 128, MAXR / 128), 256, 0, stream>>>(
      Hb, W2T_all, b2, seg, tokl, wgt, slt, nullptr, eoSb);

  // 9) final residual LN
  final_kernel<<<dim3(NT), 256, 0, stream>>>(eoSb, xf, qres, g_out, b_out, out);
}

// Round 11
// 354.837 us; speedup vs baseline: 1.1335x; 1.0646x over previous
//
#include <hip/hip_runtime.h>
#include <math.h>

typedef __attribute__((ext_vector_type(8))) short short8;
typedef __attribute__((ext_vector_type(4))) float f32x4;

#define LN_EPS 1e-5f

__device__ __forceinline__ float bf2f(unsigned short u) {
  unsigned int x = ((unsigned int)u) << 16;
  float f;
  __builtin_memcpy(&f, &x, 4);
  return f;
}
__device__ __forceinline__ unsigned short f2bf(float f) {
  unsigned int x;
  __builtin_memcpy(&x, &f, 4);
  x += 0x7fffu + ((x >> 16) & 1u);
  return (unsigned short)(x >> 16);
}

__device__ __forceinline__ void gload16(const void* g, void* l) {
  __builtin_amdgcn_global_load_lds(
      (__attribute__((address_space(1))) void*)(void*)g,
      (__attribute__((address_space(3))) void*)l, 16, 0, 0);
}

// bijective chunked XCD swizzle (requires nx*ny % 8 == 0)
__device__ __forceinline__ void xcd_swizzle(int& bx, int& by) {
  const int nx = gridDim.x;
  const int nwg = nx * gridDim.y;
  const int orig = blockIdx.y * nx + blockIdx.x;
  const int cpx = nwg >> 3;
  const int lid = (orig & 7) * cpx + (orig >> 3);
  bx = lid % nx;
  by = lid / nx;
}

// ---------------- block reduce (sum, sumsq) over 256 threads ----------------
__device__ __forceinline__ void blockReduce2(float& a, float& b, float* s8) {
#pragma unroll
  for (int off = 32; off > 0; off >>= 1) {
    a += __shfl_down(a, off);
    b += __shfl_down(b, off);
  }
  const int w = threadIdx.x >> 6;
  if ((threadIdx.x & 63) == 0) { s8[w] = a; s8[4 + w] = b; }
  __syncthreads();
  a = s8[0] + s8[1] + s8[2] + s8[3];
  b = s8[4] + s8[5] + s8[6] + s8[7];
}

// ------- fused prep: blocks 0..4095 transpose Wq/Wk/Wv/Wo (f32->bf16, [K][N]->[N][K]);
//         blocks 4096..16383 = LN(q,k,v) -> bf16 -------
__global__ __launch_bounds__(256) void prep_kernel(
    const float* __restrict__ q, const float* __restrict__ k, const float* __restrict__ v,
    const float* __restrict__ gq, const float* __restrict__ bq,
    const float* __restrict__ gk, const float* __restrict__ bk,
    const float* __restrict__ gv, const float* __restrict__ bv,
    const float* __restrict__ Wq, const float* __restrict__ Wk,
    const float* __restrict__ Wv, const float* __restrict__ Wo,
    unsigned short* __restrict__ oq, unsigned short* __restrict__ ok,
    unsigned short* __restrict__ ov,
    unsigned short* __restrict__ WqT, unsigned short* __restrict__ WkT,
    unsigned short* __restrict__ WvT, unsigned short* __restrict__ WoT) {
  __shared__ float t[32][33];
  __shared__ float s8[8];
  const int id = blockIdx.x;
  if (id < 4096) {
    const int which = id >> 10, tile = id & 1023;
    const int bx = tile & 31, by = tile >> 5;
    const float* src = which == 0 ? Wq : which == 1 ? Wk : which == 2 ? Wv : Wo;
    unsigned short* dst = which == 0 ? WqT : which == 1 ? WkT : which == 2 ? WvT : WoT;
    const int tx = threadIdx.x & 31, ty = threadIdx.x >> 5;
#pragma unroll
    for (int i = 0; i < 32; i += 8)
      t[ty + i][tx] = src[(size_t)(by * 32 + ty + i) * 1024 + bx * 32 + tx];
    __syncthreads();
#pragma unroll
    for (int i = 0; i < 32; i += 8)
      dst[(size_t)(bx * 32 + ty + i) * 1024 + by * 32 + tx] = f2bf(t[tx][ty + i]);
  } else {
    const int r = id - 4096;
    const int which = r >> 12, row = r & 4095;
    const float* x = which == 0 ? q : which == 1 ? k : v;
    const float* g = which == 0 ? gq : which == 1 ? gk : gv;
    const float* b = which == 0 ? bq : which == 1 ? bk : bv;
    unsigned short* o = which == 0 ? oq : which == 1 ? ok : ov;
    const float4 xv = ((const float4*)(x + (size_t)row * 1024))[threadIdx.x];
    float s = xv.x + xv.y + xv.z + xv.w;
    float s2 = xv.x * xv.x + xv.y * xv.y + xv.z * xv.z + xv.w * xv.w;
    blockReduce2(s, s2, s8);
    const float mu = s * (1.f / 1024.f);
    const float rs = rsqrtf(s2 * (1.f / 1024.f) - mu * mu + LN_EPS);
    const int c = threadIdx.x * 4;
    const float y[4] = {xv.x, xv.y, xv.z, xv.w};
#pragma unroll
    for (int j = 0; j < 4; ++j)
      o[(size_t)row * 1024 + c + j] = f2bf((y[j] - mu) * rs * g[c + j] + b[c + j]);
  }
}

// ------- fused: LN(q_res) -> xf,xb AND router logits/softmax/top2 (NO atomics) -------
__global__ __launch_bounds__(256) void ln_moe_router_kernel(
    const float* __restrict__ qres, const float* __restrict__ g, const float* __restrict__ b,
    const float* __restrict__ Wr, const float* __restrict__ br,
    const float* __restrict__ noise,
    float* __restrict__ xf, unsigned short* __restrict__ xb,
    int* __restrict__ pick, float* __restrict__ pw) {
  __shared__ float s8[8];
  __shared__ float sacc[32];
  const int row = blockIdx.x;
  const float4 xv = ((const float4*)(qres + (size_t)row * 1024))[threadIdx.x];
  float s = xv.x + xv.y + xv.z + xv.w;
  float s2 = xv.x * xv.x + xv.y * xv.y + xv.z * xv.z + xv.w * xv.w;
  blockReduce2(s, s2, s8);
  const float mu = s * (1.f / 1024.f);
  const float rs = rsqrtf(s2 * (1.f / 1024.f) - mu * mu + LN_EPS);
  const int c = threadIdx.x * 4;
  const float yin[4] = {xv.x, xv.y, xv.z, xv.w};
  float y[4];
#pragma unroll
  for (int j = 0; j < 4; ++j) {
    y[j] = (yin[j] - mu) * rs * g[c + j] + b[c + j];
    xf[(size_t)row * 1024 + c + j] = y[j];
    xb[(size_t)row * 1024 + c + j] = f2bf(y[j]);
  }
  float acc[8] = {};
  const float4* wrv = (const float4*)(Wr + (size_t)c * 8);
#pragma unroll
  for (int j = 0; j < 4; ++j) {
    const float4 w0 = wrv[j * 2], w1 = wrv[j * 2 + 1];
    acc[0] += y[j] * w0.x; acc[1] += y[j] * w0.y;
    acc[2] += y[j] * w0.z; acc[3] += y[j] * w0.w;
    acc[4] += y[j] * w1.x; acc[5] += y[j] * w1.y;
    acc[6] += y[j] * w1.z; acc[7] += y[j] * w1.w;
  }
#pragma unroll
  for (int off = 32; off > 0; off >>= 1)
#pragma unroll
    for (int e = 0; e < 8; ++e) acc[e] += __shfl_down(acc[e], off);
  const int w = threadIdx.x >> 6;
  if ((threadIdx.x & 63) == 0)
#pragma unroll
    for (int e = 0; e < 8; ++e) sacc[w * 8 + e] = acc[e];
  __syncthreads();
  if (threadIdx.x == 0) {
    float lg[8], mx = -1e30f;
#pragma unroll
    for (int e = 0; e < 8; ++e) {
      lg[e] = sacc[e] + sacc[8 + e] + sacc[16 + e] + sacc[24 + e] + br[e] +
              0.1f * noise[(size_t)row * 8 + e];
      mx = fmaxf(mx, lg[e]);
    }
    float ssum = 0.f;
#pragma unroll
    for (int e = 0; e < 8; ++e) { lg[e] = expf(lg[e] - mx); ssum += lg[e]; }
    const float inv = 1.f / ssum;
#pragma unroll
    for (int e = 0; e < 8; ++e) lg[e] *= inv;
    int i1 = -1, i2 = -1;
    float m1 = -1.f, m2 = -1.f;
#pragma unroll
    for (int e = 0; e < 8; ++e) {
      if (lg[e] > m1) { m2 = m1; i2 = i1; m1 = lg[e]; i1 = e; }
      else if (lg[e] > m2) { m2 = lg[e]; i2 = e; }
    }
    pick[row * 2] = i1; pick[row * 2 + 1] = i2;
    pw[row * 2] = m1;  pw[row * 2 + 1] = m2;
  }
}

// ------- single-block routing build (LDS atomics only), pad-to-128 -------
__global__ __launch_bounds__(1024) void route_build_kernel(
    const int* __restrict__ pick, const float* __restrict__ pw,
    int* __restrict__ seg, int* __restrict__ tok, float* __restrict__ wgt,
    int* __restrict__ slt) {
  __shared__ int cnt[8];
  __shared__ int segs[9];
  __shared__ int cur[8];
  const int tid = threadIdx.x;
  if (tid < 8) { cnt[tid] = 0; cur[tid] = 0; }
  __syncthreads();
  for (int i = tid; i < 8192; i += 1024) atomicAdd(&cnt[pick[i]], 1);
  __syncthreads();
  if (tid == 0) {
    int o = 0;
    for (int e = 0; e < 8; ++e) { segs[e] = o; o += (cnt[e] + 127) & ~127; }
    segs[8] = o;
  }
  __syncthreads();
  for (int i = tid; i < 9216; i += 1024) tok[i] = -1;
  if (tid < 9) seg[tid] = segs[tid];
  __syncthreads();
  for (int i = tid; i < 8192; i += 1024) {
    const int n = i >> 1, sl = i & 1;
    const int e = pick[i];
    const int p = atomicAdd(&cur[e], 1);
    const int gr = segs[e] + p;
    tok[gr] = n;
    wgt[gr] = pw[i];
    slt[gr] = sl;
  }
}

// ------- final: out = qres + LN(eo0 + eo1 + x); expert slots in bf16 -------
__global__ __launch_bounds__(256) void final_kernel(
    const unsigned short* __restrict__ eoSb, const float* __restrict__ xf,
    const float* __restrict__ qres, const float* __restrict__ g,
    const float* __restrict__ b, float* __restrict__ out) {
  __shared__ float s8[8];
  const int row = blockIdx.x;
  const size_t SLOT = (size_t)4096 * 1024;
  const unsigned short* p0 = eoSb + (size_t)row * 1024 + threadIdx.x * 4;
  const unsigned short* p1 = eoSb + SLOT + (size_t)row * 1024 + threadIdx.x * 4;
  const float4 xv = ((const float4*)(xf + (size_t)row * 1024))[threadIdx.x];
  float y[4];
#pragma unroll
  for (int j = 0; j < 4; ++j) y[j] = bf2f(p0[j]) + bf2f(p1[j]);
  y[0] += xv.x; y[1] += xv.y; y[2] += xv.z; y[3] += xv.w;
  float s = y[0] + y[1] + y[2] + y[3];
  float s2 = y[0] * y[0] + y[1] * y[1] + y[2] * y[2] + y[3] * y[3];
  blockReduce2(s, s2, s8);
  const float mu = s * (1.f / 1024.f);
  const float rs = rsqrtf(s2 * (1.f / 1024.f) - mu * mu + LN_EPS);
  const int c = threadIdx.x * 4;
#pragma unroll
  for (int j = 0; j < 4; ++j) {
    const size_t idx = (size_t)row * 1024 + c + j;
    out[idx] = qres[idx] + (y[j] - mu) * rs * g[c + j] + b[c + j];
  }
}

// ------- merged expert weight transpose: z<8 -> W1[e], z>=8 -> W2[e-8] -------
__global__ __launch_bounds__(256) void transpose16_kernel(
    const float* __restrict__ W1, const float* __restrict__ W2,
    unsigned short* __restrict__ W1T, unsigned short* __restrict__ W2T) {
  __shared__ float t[32][33];
  const int z = blockIdx.y;
  const bool isW1 = z < 8;
  const int e = isW1 ? z : z - 8;
  const int R = isW1 ? 1024 : 2048;
  const int C = isW1 ? 2048 : 1024;
  const float* src = (isW1 ? W1 : W2) + (size_t)e * 1024 * 2048;
  unsigned short* dst = (isW1 ? W1T : W2T) + (size_t)e * 1024 * 2048;
  const int tcols = C >> 5;
  const int by = blockIdx.x / tcols, bx = blockIdx.x % tcols;
  const int tx = threadIdx.x & 31, ty = threadIdx.x >> 5;
#pragma unroll
  for (int i = 0; i < 32; i += 8)
    t[ty + i][tx] = src[(size_t)(by * 32 + ty + i) * C + bx * 32 + tx];
  __syncthreads();
#pragma unroll
  for (int i = 0; i < 32; i += 8)
    dst[(size_t)(bx * 32 + ty + i) * R + by * 32 + tx] = f2bf(t[tx][ty + i]);
}

// ========== Core A: 128x128 tile, BK=32, 256 thr, dbuf + chunk-XOR swizzle ==========
// LDS rows are 64B (4 x 16B chunks). f(row) = (row>>1)&3 XORs the chunk index:
// stage source chunk = (lane&3)^((lane>>3)&3)  [gload_lds dest stays linear],
// read chunk = (lane>>4)^((lane>>1)&3)  -> 2-way bank aliasing (free). Verified r10: 0 conflicts.
#define GEMM_STAGE(buf, k0, KD)                                              \
  gload16(gA0 + (k0), lA + (buf) * 4096);                                    \
  gload16(gA1 + (k0), lA + (buf) * 4096 + 16 * 32);                          \
  gload16(gB + (k0), lB + (buf) * 4096);                                     \
  gload16(gB + (size_t)16 * (KD) + (k0), lB + (buf) * 4096 + 16 * 32);

#define GEMM_COMPUTE(buf)                                                    \
  {                                                                          \
    const unsigned short* sA = &As[buf][0];                                  \
    const unsigned short* sB = &Bs[buf][0];                                  \
    short8 af[4], bfr[4];                                                    \
    _Pragma("unroll") for (int m = 0; m < 4; ++m)                            \
        af[m] = *(const short8*)&sA[(arow + m * 16) * 32 + kksw];            \
    _Pragma("unroll") for (int n = 0; n < 4; ++n)                            \
        bfr[n] = *(const short8*)&sB[(brow + n * 16) * 32 + kksw];           \
    _Pragma("unroll") for (int m = 0; m < 4; ++m)                            \
      _Pragma("unroll") for (int n = 0; n < 4; ++n)                          \
        acc[m][n] = __builtin_amdgcn_mfma_f32_16x16x32_bf16(                 \
            af[m], bfr[n], acc[m][n], 0, 0, 0);                              \
  }

#define GEMM_LOOP(KD)                                                        \
  GEMM_STAGE(0, 0, KD)                                                       \
  __syncthreads();                                                           \
  for (int k0 = 0; k0 < (KD); k0 += 64) {                                    \
    GEMM_STAGE(1, k0 + 32, KD)                                               \
    GEMM_COMPUTE(0)                                                          \
    __syncthreads();                                                         \
    if (k0 + 64 < (KD)) { GEMM_STAGE(0, k0 + 64, KD) }                       \
    GEMM_COMPUTE(1)                                                          \
    __syncthreads();                                                         \
  }

#define GEMM_PREAMBLE                                                        \
  __shared__ __align__(16) unsigned short As[2][128 * 32];                   \
  __shared__ __align__(16) unsigned short Bs[2][128 * 32];                   \
  const int tid = threadIdx.x;                                               \
  const int lane = tid & 63, w = tid >> 6;                                   \
  const int wr = w >> 1, wc = w & 1;                                         \
  const int sr = lane >> 2;                                                  \
  const int sc = (((lane & 3) ^ ((lane >> 3) & 3)) * 8); /* swizzled src */  \
  const int arow = wr * 64 + (lane & 15);                                    \
  const int brow = wc * 64 + (lane & 15);                                    \
  const int kksw = (((lane >> 4) ^ ((lane >> 1) & 3)) * 8); /* swz read */   \
  unsigned short* lA = &As[0][(w * 32) * 32];                                \
  unsigned short* lB = &Bs[0][(w * 32) * 32];

// fused q/k/v projection: blockIdx.z selects which; grid (8,32,3)
__global__ __launch_bounds__(256) void gemm_qkv(
    const unsigned short* __restrict__ lnq, const unsigned short* __restrict__ lnk,
    const unsigned short* __restrict__ lnv, const unsigned short* __restrict__ WqT,
    const unsigned short* __restrict__ WkT, const unsigned short* __restrict__ WvT,
    unsigned short* __restrict__ qf, unsigned short* __restrict__ kf,
    unsigned short* __restrict__ vh) {
  const int z = blockIdx.z;
  const unsigned short* A = z == 0 ? lnq : z == 1 ? lnk : lnv;
  const unsigned short* Bt = z == 0 ? WqT : z == 1 ? WkT : WvT;
  unsigned short* outb = z == 0 ? qf : z == 1 ? kf : vh;
  const int K = 1024, N = 1024;
  GEMM_PREAMBLE
  int bx, by;
  xcd_swizzle(bx, by);
  const int row0 = by * 128, col0 = bx * 128;
  const unsigned short* gA0 = A + (size_t)(row0 + w * 32 + sr) * K + sc;
  const unsigned short* gA1 = gA0 + (size_t)16 * K;
  const unsigned short* gB = Bt + (size_t)(col0 + w * 32 + sr) * K + sc;
  f32x4 acc[4][4] = {};
  GEMM_LOOP(1024)
#pragma unroll
  for (int m = 0; m < 4; ++m) {
    const int rbase = row0 + wr * 64 + m * 16 + (lane >> 4) * 4;
#pragma unroll
    for (int n = 0; n < 4; ++n) {
      const int c = col0 + wc * 64 + n * 16 + (lane & 15);
#pragma unroll
      for (int r = 0; r < 4; ++r) {
        float v = acc[m][n][r];
        if (z < 2) v = v > 0.f ? v + 1.f : __expf(v);  // elu+1
        outb[(size_t)(rbase + r) * N + c] = f2bf(v);
      }
    }
  }
}

// Wo projection + bias + residual -> qres (f32); grid (8,32)
__global__ __launch_bounds__(256) void gemm_wo(
    const unsigned short* __restrict__ A, const unsigned short* __restrict__ Bt,
    float* __restrict__ outf, const float* __restrict__ bias,
    const float* __restrict__ addm) {
  const int K = 1024, N = 1024;
  GEMM_PREAMBLE
  int bx, by;
  xcd_swizzle(bx, by);
  const int row0 = by * 128, col0 = bx * 128;
  const unsigned short* gA0 = A + (size_t)(row0 + w * 32 + sr) * K + sc;
  const unsigned short* gA1 = gA0 + (size_t)16 * K;
  const unsigned short* gB = Bt + (size_t)(col0 + w * 32 + sr) * K + sc;
  f32x4 acc[4][4] = {};
  GEMM_LOOP(1024)
#pragma unroll
  for (int m = 0; m < 4; ++m) {
    const int rbase = row0 + wr * 64 + m * 16 + (lane >> 4) * 4;
#pragma unroll
    for (int n = 0; n < 4; ++n) {
      const int c = col0 + wc * 64 + n * 16 + (lane & 15);
#pragma unroll
      for (int r = 0; r < 4; ++r) {
        const size_t idx = (size_t)(rbase + r) * N + c;
        outf[idx] = acc[m][n][r] + bias[c] + addm[idx];
      }
    }
  }
}

// ---------------- gathered MoE GEMM (Core A; phase-2 writes bf16 slots) ----------------
template <int PHASE>
__global__ __launch_bounds__(256) void gemm_moe(
    const unsigned short* __restrict__ Asrc, const unsigned short* __restrict__ Ball,
    const float* __restrict__ bias_all,
    const int* __restrict__ seg, const int* __restrict__ tok,
    const float* __restrict__ wgt, const int* __restrict__ slt,
    unsigned short* __restrict__ Hb, unsigned short* __restrict__ eoSb) {
  constexpr int K = (PHASE == 1) ? 1024 : 2048;
  constexpr int N = (PHASE == 1) ? 2048 : 1024;
  GEMM_PREAMBLE
  int bx, by;
  xcd_swizzle(bx, by);
  const int row0 = by * 128;
  if (row0 >= seg[8]) return;
  int e = 0;
  while (e < 7 && row0 >= seg[e + 1]) ++e;
  const int col0 = bx * 128;
  const unsigned short* Bt = Ball + (size_t)e * N * K;
  const int gr0 = row0 + w * 32 + sr;
  const int gr1 = gr0 + 16;
  const unsigned short* gA0;
  const unsigned short* gA1;
  if constexpr (PHASE == 1) {
    const int t0 = tok[gr0], t1 = tok[gr1];
    gA0 = Asrc + (size_t)(t0 < 0 ? 0 : t0) * K + sc;
    gA1 = Asrc + (size_t)(t1 < 0 ? 0 : t1) * K + sc;
  } else {
    gA0 = Asrc + (size_t)gr0 * K + sc;
    gA1 = Asrc + (size_t)gr1 * K + sc;
  }
  const unsigned short* gB = Bt + (size_t)(col0 + w * 32 + sr) * K + sc;
  f32x4 acc[4][4] = {};
  if constexpr (PHASE == 1) { GEMM_LOOP(1024) }
  else { GEMM_LOOP(2048) }
  const float* bias = bias_all + (size_t)e * N;
#pragma unroll
  for (int m = 0; m < 4; ++m) {
    const int rloc = wr * 64 + m * 16 + (lane >> 4) * 4;
#pragma unroll
    for (int n = 0; n < 4; ++n) {
      const int c = col0 + wc * 64 + n * 16 + (lane & 15);
#pragma unroll
      for (int r = 0; r < 4; ++r) {
        const int gr = row0 + rloc + r;
        float v = acc[m][n][r] + bias[c];
        if constexpr (PHASE == 1) {
          // gelu via tanh-form: 0.5v(1+tanh(t)) = v*sigmoid(2t); max dev ~1e-3
          float t2 = v * (1.59576912f + 0.07135481f * v * v);
          t2 = fminf(t2, 30.f);
          const float eg = __expf(t2);
          v = v * eg * __builtin_amdgcn_rcpf(eg + 1.f);
          Hb[(size_t)gr * 2048 + c] = f2bf(v);
        } else {
          const int tkn = tok[gr];
          if (tkn >= 0)
            eoSb[(size_t)slt[gr] * (4096 * 1024) + (size_t)tkn * 1024 + c] =
                f2bf(wgt[gr] * v);
        }
      }
    }
  }
}

// ---------------- attention: kv partials (bf16 partial store) ----------------
__global__ __launch_bounds__(256) void kvpart_kernel(
    const unsigned short* __restrict__ kf, const unsigned short* __restrict__ vh,
    unsigned short* __restrict__ kvp, float* __restrict__ ksp) {
  const int bh = blockIdx.x;
  const int b = bh >> 3, h = bh & 7;
  const int ch = blockIdx.y;
  const int tid = threadIdx.x;
  const int d0 = (tid >> 4) * 8, e0 = (tid & 15) * 8;
  __shared__ unsigned short kb[64][128];
  __shared__ unsigned short vb[64][128];
  for (int i = tid; i < 1024; i += 256) {
    const int tt = i >> 4, dd = (i & 15) * 8;
    const size_t base = ((size_t)((b * 1024 + ch * 64 + tt) * 8 + h)) * 128 + dd;
    *(short8*)&kb[tt][dd] = *(const short8*)&kf[base];
    *(short8*)&vb[tt][dd] = *(const short8*)&vh[base];
  }
  __syncthreads();
  float acc[8][8] = {};
  float ks[8] = {};
  for (int tt = 0; tt < 64; ++tt) {
    float kv8[8], vv8[8];
    const short8 kr = *(const short8*)&kb[tt][d0];
    const short8 vr = *(const short8*)&vb[tt][e0];
#pragma unroll
    for (int j = 0; j < 8; ++j) {
      kv8[j] = bf2f((unsigned short)kr[j]);
      vv8[j] = bf2f((unsigned short)vr[j]);
    }
#pragma unroll
    for (int i = 0; i < 8; ++i)
#pragma unroll
      for (int j = 0; j < 8; ++j) acc[i][j] += kv8[i] * vv8[j];
    if ((tid & 15) == 0)
#pragma unroll
      for (int i = 0; i < 8; ++i) ks[i] += kv8[i];
  }
  const size_t obase = ((size_t)(ch * 32 + bh) * 128) * 128;
#pragma unroll
  for (int i = 0; i < 8; ++i)
#pragma unroll
    for (int j = 0; j < 8; ++j)
      kvp[obase + (size_t)(d0 + i) * 128 + e0 + j] = f2bf(acc[i][j]);
  if ((tid & 15) == 0)
#pragma unroll
    for (int i = 0; i < 8; ++i) ksp[(size_t)(ch * 32 + bh) * 128 + d0 + i] = ks[i];
}

__global__ __launch_bounds__(256) void kvreduce_kernel(
    const unsigned short* __restrict__ kvp, const float* __restrict__ ksp,
    unsigned short* __restrict__ kvb, float* __restrict__ ksum) {
  const int idx = blockIdx.x * 256 + threadIdx.x;
  const int CS = 32 * 128 * 128;
  float s = 0.f;
#pragma unroll
  for (int c = 0; c < 16; ++c) s += bf2f(kvp[(size_t)c * CS + idx]);
  kvb[idx] = f2bf(s);
  if (idx < 32 * 128) {
    float t = 1e-6f;
#pragma unroll
    for (int c = 0; c < 16; ++c) t += ksp[c * 4096 + idx];
    ksum[idx] = t;
  }
}

__global__ __launch_bounds__(256) void attnout_kernel(
    const unsigned short* __restrict__ qf, const unsigned short* __restrict__ kvb,
    const float* __restrict__ ksum, unsigned short* __restrict__ ctx) {
  const int bh = blockIdx.x, b = bh >> 3, h = bh & 7;
  const int tb = blockIdx.y;
  const int tid = threadIdx.x;
  __shared__ unsigned short kvl[128 * 128];
  __shared__ float ksl[128];
  __shared__ float denom[128];
  __shared__ unsigned short qfl[128 * 32];
  for (int i = tid; i < 16384; i += 256) kvl[i] = kvb[(size_t)bh * 16384 + i];
  if (tid < 128) ksl[tid] = ksum[bh * 128 + tid];
  __syncthreads();
  if (tid < 128) {
    const int t = tb * 128 + tid;
    const size_t qbase = ((size_t)((b * 1024 + t) * 8 + h)) * 128;
    float s = 0.f;
    for (int d = 0; d < 128; ++d) s += bf2f(qf[qbase + d]) * ksl[d];
    denom[tid] = s;
  }
  float acc[8][8] = {};
  const int t0 = (tid >> 4) * 8, e0 = (tid & 15) * 8;
  for (int dc = 0; dc < 128; dc += 32) {
    __syncthreads();
    for (int i = tid; i < 128 * 32; i += 256) {
      const int tt = i >> 5, dd = i & 31;
      qfl[i] = qf[((size_t)((b * 1024 + tb * 128 + tt) * 8 + h)) * 128 + dc + dd];
    }
    __syncthreads();
    for (int dd = 0; dd < 32; ++dd) {
      float kvrow[8];
#pragma unroll
      for (int j = 0; j < 8; ++j) kvrow[j] = bf2f(kvl[(dc + dd) * 128 + e0 + j]);
#pragma unroll
      for (int i = 0; i < 8; ++i) {
        const float qv = bf2f(qfl[(t0 + i) * 32 + dd]);
#pragma unroll
        for (int j = 0; j < 8; ++j) acc[i][j] += qv * kvrow[j];
      }
    }
  }
  __syncthreads();
#pragma unroll
  for (int i = 0; i < 8; ++i) {
    const int t = tb * 128 + t0 + i;
    const float inv = 1.f / denom[t0 + i];
#pragma unroll
    for (int j = 0; j < 8; ++j)
      ctx[((size_t)(b * 1024 + t)) * 1024 + h * 128 + e0 + j] = f2bf(acc[i][j] * inv);
  }
}

// ---------------- host launcher ----------------
extern "C" void kernel_launch(void* const* d_in, const int* in_sizes, int n_in,
                              void* d_out, int out_size, void* d_ws, size_t ws_size,
                              hipStream_t stream) {
  (void)in_sizes; (void)n_in; (void)out_size; (void)ws_size;
  const float* vin  = (const float*)d_in[0];
  const float* kin  = (const float*)d_in[1];
  const float* qin  = (const float*)d_in[2];
  const float* noise = (const float*)d_in[3];
  const float* g_v = (const float*)d_in[4];  const float* b_v = (const float*)d_in[5];
  const float* g_k = (const float*)d_in[6];  const float* b_k = (const float*)d_in[7];
  const float* g_q = (const float*)d_in[8];  const float* b_q = (const float*)d_in[9];
  const float* g_moe = (const float*)d_in[10]; const float* b_moe = (const float*)d_in[11];
  const float* g_out = (const float*)d_in[12]; const float* b_out = (const float*)d_in[13];
  const float* Wq = (const float*)d_in[14];
  const float* Wk = (const float*)d_in[15];
  const float* Wv = (const float*)d_in[16];
  const float* Wo = (const float*)d_in[17];
  const float* bo = (const float*)d_in[18];
  const float* Wr = (const float*)d_in[19];
  const float* br = (const float*)d_in[20];
  const float* W1 = (const float*)d_in[21];
  const float* b1 = (const float*)d_in[22];
  const float* W2 = (const float*)d_in[23];
  const float* b2 = (const float*)d_in[24];
  float* out = (float*)d_out;

  const int NT = 4096, D = 1024, FF = 2048;
  const int MAXR = 9216;  // 8192 pairs + per-expert pad to 128

  char* p = (char*)d_ws;
  auto alloc = [&](size_t bytes) {
    void* r = (void*)p;
    p += (bytes + 255) & ~(size_t)255;
    return r;
  };
  char* base0 = p;
  unsigned short* lnq = (unsigned short*)alloc((size_t)NT * D * 2);
  unsigned short* lnk = (unsigned short*)alloc((size_t)NT * D * 2);
  unsigned short* lnv = (unsigned short*)alloc((size_t)NT * D * 2);
  unsigned short* WqT = (unsigned short*)alloc((size_t)D * D * 2);
  unsigned short* WkT = (unsigned short*)alloc((size_t)D * D * 2);
  unsigned short* WvT = (unsigned short*)alloc((size_t)D * D * 2);
  unsigned short* WoT = (unsigned short*)alloc((size_t)D * D * 2);
  unsigned short* qf  = (unsigned short*)alloc((size_t)NT * D * 2);
  unsigned short* kf  = (unsigned short*)alloc((size_t)NT * D * 2);
  unsigned short* vh  = (unsigned short*)alloc((size_t)NT * D * 2);
  unsigned short* kvb = (unsigned short*)alloc((size_t)32 * 128 * 128 * 2);
  float* ksp  = (float*)alloc((size_t)16 * 32 * 128 * 4);
  float* ksum = (float*)alloc((size_t)32 * 128 * 4);
  unsigned short* ctx = (unsigned short*)alloc((size_t)NT * D * 2);
  float* qres = (float*)alloc((size_t)NT * D * 4);
  float* xf   = (float*)alloc((size_t)NT * D * 4);
  unsigned short* xb = (unsigned short*)alloc((size_t)NT * D * 2);
  unsigned short* W1T_all = (unsigned short*)alloc((size_t)8 * D * FF * 2);
  unsigned short* W2T_all = (unsigned short*)alloc((size_t)8 * FF * D * 2);
  unsigned short* kvp = (unsigned short*)alloc((size_t)16 * 32 * 128 * 128 * 2);  // bf16
  unsigned short* eoSb = (unsigned short*)alloc((size_t)2 * NT * D * 2);  // bf16 slots
  int* pick = (int*)alloc((size_t)NT * 2 * 4);
  float* pw = (float*)alloc((size_t)NT * 2 * 4);
  int* seg = (int*)alloc(9 * 4);
  int* tokl = (int*)alloc(MAXR * 4);
  float* wgt = (float*)alloc(MAXR * 4);
  int* slt = (int*)alloc(MAXR * 4);
  unsigned short* Hb = (unsigned short*)base0;  // 36MB alias over dead early bufs

  // 1) fused prep: Wq/Wk/Wv/Wo transposes + LN(q,k,v)
  prep_kernel<<<dim3(16384), 256, 0, stream>>>(
      qin, kin, vin, g_q, b_q, g_k, b_k, g_v, b_v, Wq, Wk, Wv, Wo,
      lnq, lnk, lnv, WqT, WkT, WvT, WoT);

  // 2) fused q/k/v projections (Core A, 768 blocks)
  gemm_qkv<<<dim3(D / 128, NT / 128, 3), 256, 0, stream>>>(lnq, lnk, lnv, WqT, WkT, WvT,
                                                           qf, kf, vh);

  // 3) linear attention state
  kvpart_kernel<<<dim3(32, 16), 256, 0, stream>>>(kf, vh, kvp, ksp);
  kvreduce_kernel<<<dim3(2048), 256, 0, stream>>>(kvp, ksp, kvb, ksum);
  attnout_kernel<<<dim3(32, 8), 256, 0, stream>>>(qf, kvb, ksum, ctx);

  // 4) out projection + bias + residual q -> q_res
  gemm_wo<<<dim3(D / 128, NT / 128), 256, 0, stream>>>(ctx, WoT, qres, bo, qin);

  // 5) fused MoE pre-LN/router + single-block routing build
  ln_moe_router_kernel<<<dim3(NT), 256, 0, stream>>>(qres, g_moe, b_moe, Wr, br, noise,
                                                     xf, xb, pick, pw);
  route_build_kernel<<<dim3(1), 1024, 0, stream>>>(pick, pw, seg, tokl, wgt, slt);

  // 6) expert weight transposes (one launch, z=0..15)
  transpose16_kernel<<<dim3(2048, 16), 256, 0, stream>>>(W1, W2, W1T_all, W2T_all);

  // 7) gathered expert GEMMs (Core A)
  gemm_moe<1><<<dim3(FF / 128, MAXR / 128), 256, 0, stream>>>(
      xb, W1T_all, b1, seg, tokl, wgt, slt, Hb, nullptr);
  gemm_moe<2><<<dim3(D / 128, MAXR / 128), 256, 0, stream>>>(
      Hb, W2T_all, b2, seg, tokl, wgt, slt, nullptr, eoSb);

  // 8) final residual LN
  final_kernel<<<dim3(NT), 256, 0, stream>>>(eoSb, xf, qres, g_out, b_out, out);
}

// Round 13
// 349.163 us; speedup vs baseline: 1.1519x; 1.0163x over previous
//
#include <hip/hip_runtime.h>
#include <math.h>

typedef __attribute__((ext_vector_type(8))) short short8;
typedef __attribute__((ext_vector_type(4))) float f32x4;

#define LN_EPS 1e-5f

__device__ __forceinline__ float bf2f(unsigned short u) {
  unsigned int x = ((unsigned int)u) << 16;
  float f;
  __builtin_memcpy(&f, &x, 4);
  return f;
}
__device__ __forceinline__ unsigned short f2bf(float f) {
  unsigned int x;
  __builtin_memcpy(&x, &f, 4);
  x += 0x7fffu + ((x >> 16) & 1u);
  return (unsigned short)(x >> 16);
}

__device__ __forceinline__ void gload16(const void* g, void* l) {
  __builtin_amdgcn_global_load_lds(
      (__attribute__((address_space(1))) void*)(void*)g,
      (__attribute__((address_space(3))) void*)l, 16, 0, 0);
}

// bijective chunked XCD swizzle (requires nx*ny % 8 == 0)
__device__ __forceinline__ void xcd_swizzle(int& bx, int& by) {
  const int nx = gridDim.x;
  const int nwg = nx * gridDim.y;
  const int orig = blockIdx.y * nx + blockIdx.x;
  const int cpx = nwg >> 3;
  const int lid = (orig & 7) * cpx + (orig >> 3);
  bx = lid % nx;
  by = lid / nx;
}

// ---------------- block reduce (sum, sumsq) over 256 threads ----------------
__device__ __forceinline__ void blockReduce2(float& a, float& b, float* s8) {
#pragma unroll
  for (int off = 32; off > 0; off >>= 1) {
    a += __shfl_down(a, off);
    b += __shfl_down(b, off);
  }
  const int w = threadIdx.x >> 6;
  if ((threadIdx.x & 63) == 0) { s8[w] = a; s8[4 + w] = b; }
  __syncthreads();
  a = s8[0] + s8[1] + s8[2] + s8[3];
  b = s8[4] + s8[5] + s8[6] + s8[7];
}

// ------- fused prep:
//   blocks [0,4096)        : transpose Wq/Wk/Wv/Wo (f32->bf16, [K][N]->[N][K])
//   blocks [4096,16384)    : LN(q,k,v) -> bf16
//   blocks [16384,49152)   : transpose expert W1/W2 (f32->bf16)
__global__ __launch_bounds__(256) void prep_kernel(
    const float* __restrict__ q, const float* __restrict__ k, const float* __restrict__ v,
    const float* __restrict__ gq, const float* __restrict__ bq,
    const float* __restrict__ gk, const float* __restrict__ bk,
    const float* __restrict__ gv, const float* __restrict__ bv,
    const float* __restrict__ Wq, const float* __restrict__ Wk,
    const float* __restrict__ Wv, const float* __restrict__ Wo,
    const float* __restrict__ W1, const float* __restrict__ W2,
    unsigned short* __restrict__ oq, unsigned short* __restrict__ ok,
    unsigned short* __restrict__ ov,
    unsigned short* __restrict__ WqT, unsigned short* __restrict__ WkT,
    unsigned short* __restrict__ WvT, unsigned short* __restrict__ WoT,
    unsigned short* __restrict__ W1T, unsigned short* __restrict__ W2T) {
  __shared__ float t[32][33];
  __shared__ float s8[8];
  const int id = blockIdx.x;
  if (id < 4096) {
    const int which = id >> 10, tile = id & 1023;
    const int bx = tile & 31, by = tile >> 5;
    const float* src = which == 0 ? Wq : which == 1 ? Wk : which == 2 ? Wv : Wo;
    unsigned short* dst = which == 0 ? WqT : which == 1 ? WkT : which == 2 ? WvT : WoT;
    const int tx = threadIdx.x & 31, ty = threadIdx.x >> 5;
#pragma unroll
    for (int i = 0; i < 32; i += 8)
      t[ty + i][tx] = src[(size_t)(by * 32 + ty + i) * 1024 + bx * 32 + tx];
    __syncthreads();
#pragma unroll
    for (int i = 0; i < 32; i += 8)
      dst[(size_t)(bx * 32 + ty + i) * 1024 + by * 32 + tx] = f2bf(t[tx][ty + i]);
  } else if (id < 16384) {
    const int r = id - 4096;
    const int which = r >> 12, row = r & 4095;
    const float* x = which == 0 ? q : which == 1 ? k : v;
    const float* g = which == 0 ? gq : which == 1 ? gk : gv;
    const float* b = which == 0 ? bq : which == 1 ? bk : bv;
    unsigned short* o = which == 0 ? oq : which == 1 ? ok : ov;
    const float4 xv = ((const float4*)(x + (size_t)row * 1024))[threadIdx.x];
    float s = xv.x + xv.y + xv.z + xv.w;
    float s2 = xv.x * xv.x + xv.y * xv.y + xv.z * xv.z + xv.w * xv.w;
    blockReduce2(s, s2, s8);
    const float mu = s * (1.f / 1024.f);
    const float rs = rsqrtf(s2 * (1.f / 1024.f) - mu * mu + LN_EPS);
    const int c = threadIdx.x * 4;
    const float y[4] = {xv.x, xv.y, xv.z, xv.w};
#pragma unroll
    for (int j = 0; j < 4; ++j)
      o[(size_t)row * 1024 + c + j] = f2bf((y[j] - mu) * rs * g[c + j] + b[c + j]);
  } else {
    const int r = id - 16384;
    const int z = r >> 11, tile = r & 2047;
    const bool isW1 = z < 8;
    const int e = isW1 ? z : z - 8;
    const int R = isW1 ? 1024 : 2048;
    const int C = isW1 ? 2048 : 1024;
    const float* src = (isW1 ? W1 : W2) + (size_t)e * 1024 * 2048;
    unsigned short* dst = (isW1 ? W1T : W2T) + (size_t)e * 1024 * 2048;
    const int tcols = C >> 5;
    const int by = tile / tcols, bx = tile % tcols;
    const int tx = threadIdx.x & 31, ty = threadIdx.x >> 5;
#pragma unroll
    for (int i = 0; i < 32; i += 8)
      t[ty + i][tx] = src[(size_t)(by * 32 + ty + i) * C + bx * 32 + tx];
    __syncthreads();
#pragma unroll
    for (int i = 0; i < 32; i += 8)
      dst[(size_t)(bx * 32 + ty + i) * R + by * 32 + tx] = f2bf(t[tx][ty + i]);
  }
}

// ------- fused: LN(q_res f32) -> xb (bf16) AND router logits/softmax/top2 -------
// NOTE: qres MUST be f32 here — routing top-2 picks are a discrete function of x;
// bf16-rounding qres flips near-tied picks and breaks accuracy (round-12 failure).
__global__ __launch_bounds__(256) void ln_moe_router_kernel(
    const float* __restrict__ qres, const float* __restrict__ g,
    const float* __restrict__ b, const float* __restrict__ Wr,
    const float* __restrict__ br, const float* __restrict__ noise,
    unsigned short* __restrict__ xb, int* __restrict__ pick, float* __restrict__ pw) {
  __shared__ float s8[8];
  __shared__ float sacc[32];
  const int row = blockIdx.x;
  const float4 xv = ((const float4*)(qres + (size_t)row * 1024))[threadIdx.x];
  float s = xv.x + xv.y + xv.z + xv.w;
  float s2 = xv.x * xv.x + xv.y * xv.y + xv.z * xv.z + xv.w * xv.w;
  blockReduce2(s, s2, s8);
  const float mu = s * (1.f / 1024.f);
  const float rs = rsqrtf(s2 * (1.f / 1024.f) - mu * mu + LN_EPS);
  const int c = threadIdx.x * 4;
  const float yin[4] = {xv.x, xv.y, xv.z, xv.w};
  float y[4];
#pragma unroll
  for (int j = 0; j < 4; ++j) {
    y[j] = (yin[j] - mu) * rs * g[c + j] + b[c + j];
    xb[(size_t)row * 1024 + c + j] = f2bf(y[j]);
  }
  float acc[8] = {};
  const float4* wrv = (const float4*)(Wr + (size_t)c * 8);
#pragma unroll
  for (int j = 0; j < 4; ++j) {
    const float4 w0 = wrv[j * 2], w1 = wrv[j * 2 + 1];
    acc[0] += y[j] * w0.x; acc[1] += y[j] * w0.y;
    acc[2] += y[j] * w0.z; acc[3] += y[j] * w0.w;
    acc[4] += y[j] * w1.x; acc[5] += y[j] * w1.y;
    acc[6] += y[j] * w1.z; acc[7] += y[j] * w1.w;
  }
#pragma unroll
  for (int off = 32; off > 0; off >>= 1)
#pragma unroll
    for (int e = 0; e < 8; ++e) acc[e] += __shfl_down(acc[e], off);
  const int w = threadIdx.x >> 6;
  if ((threadIdx.x & 63) == 0)
#pragma unroll
    for (int e = 0; e < 8; ++e) sacc[w * 8 + e] = acc[e];
  __syncthreads();
  if (threadIdx.x == 0) {
    float lg[8], mx = -1e30f;
#pragma unroll
    for (int e = 0; e < 8; ++e) {
      lg[e] = sacc[e] + sacc[8 + e] + sacc[16 + e] + sacc[24 + e] + br[e] +
              0.1f * noise[(size_t)row * 8 + e];
      mx = fmaxf(mx, lg[e]);
    }
    float ssum = 0.f;
#pragma unroll
    for (int e = 0; e < 8; ++e) { lg[e] = expf(lg[e] - mx); ssum += lg[e]; }
    const float inv = 1.f / ssum;
#pragma unroll
    for (int e = 0; e < 8; ++e) lg[e] *= inv;
    int i1 = -1, i2 = -1;
    float m1 = -1.f, m2 = -1.f;
#pragma unroll
    for (int e = 0; e < 8; ++e) {
      if (lg[e] > m1) { m2 = m1; i2 = i1; m1 = lg[e]; i1 = e; }
      else if (lg[e] > m2) { m2 = lg[e]; i2 = e; }
    }
    pick[row * 2] = i1; pick[row * 2 + 1] = i2;
    pw[row * 2] = m1;  pw[row * 2 + 1] = m2;
  }
}

// ------- single-block routing build (LDS atomics only), pad-to-128 -------
__global__ __launch_bounds__(1024) void route_build_kernel(
    const int* __restrict__ pick, const float* __restrict__ pw,
    int* __restrict__ seg, int* __restrict__ tok, float* __restrict__ wgt,
    int* __restrict__ slt) {
  __shared__ int cnt[8];
  __shared__ int segs[9];
  __shared__ int cur[8];
  const int tid = threadIdx.x;
  if (tid < 8) { cnt[tid] = 0; cur[tid] = 0; }
  __syncthreads();
  for (int i = tid; i < 8192; i += 1024) atomicAdd(&cnt[pick[i]], 1);
  __syncthreads();
  if (tid == 0) {
    int o = 0;
    for (int e = 0; e < 8; ++e) { segs[e] = o; o += (cnt[e] + 127) & ~127; }
    segs[8] = o;
  }
  __syncthreads();
  for (int i = tid; i < 9216; i += 1024) tok[i] = -1;
  if (tid < 9) seg[tid] = segs[tid];
  __syncthreads();
  for (int i = tid; i < 8192; i += 1024) {
    const int n = i >> 1, sl = i & 1;
    const int e = pick[i];
    const int p = atomicAdd(&cur[e], 1);
    const int gr = segs[e] + p;
    tok[gr] = n;
    wgt[gr] = pw[i];
    slt[gr] = sl;
  }
}

// ------- final: out = qres(f32) + LN(eo0 + eo1 + x); x/slots in bf16 -------
__global__ __launch_bounds__(256) void final_kernel(
    const unsigned short* __restrict__ eoSb, const unsigned short* __restrict__ xb,
    const float* __restrict__ qres, const float* __restrict__ g,
    const float* __restrict__ b, float* __restrict__ out) {
  __shared__ float s8[8];
  const int row = blockIdx.x;
  const size_t SLOT = (size_t)4096 * 1024;
  const size_t base = (size_t)row * 1024 + threadIdx.x * 4;
  const unsigned short* p0 = eoSb + base;
  const unsigned short* p1 = eoSb + SLOT + base;
  const unsigned short* px = xb + base;
  const float4 qv = *(const float4*)(qres + base);
  float y[4];
#pragma unroll
  for (int j = 0; j < 4; ++j) y[j] = bf2f(p0[j]) + bf2f(p1[j]) + bf2f(px[j]);
  float s = y[0] + y[1] + y[2] + y[3];
  float s2 = y[0] * y[0] + y[1] * y[1] + y[2] * y[2] + y[3] * y[3];
  blockReduce2(s, s2, s8);
  const float mu = s * (1.f / 1024.f);
  const float rs = rsqrtf(s2 * (1.f / 1024.f) - mu * mu + LN_EPS);
  const int c = threadIdx.x * 4;
  const float qarr[4] = {qv.x, qv.y, qv.z, qv.w};
#pragma unroll
  for (int j = 0; j < 4; ++j)
    out[base + j] = qarr[j] + (y[j] - mu) * rs * g[c + j] + b[c + j];
}

// ========== Core A: 128x128 tile, BK=32, 256 thr, dbuf + chunk-XOR swizzle ==========
// LDS rows are 64B (4 x 16B chunks). f(row) = (row>>1)&3 XORs the chunk index:
// stage source chunk = (lane&3)^((lane>>3)&3)  [gload_lds dest stays linear],
// read chunk = (lane>>4)^((lane>>1)&3)  -> 2-way bank aliasing (free). r10: 0 conflicts.
#define GEMM_STAGE(buf, k0, KD)                                              \
  gload16(gA0 + (k0), lA + (buf) * 4096);                                    \
  gload16(gA1 + (k0), lA + (buf) * 4096 + 16 * 32);                          \
  gload16(gB + (k0), lB + (buf) * 4096);                                     \
  gload16(gB + (size_t)16 * (KD) + (k0), lB + (buf) * 4096 + 16 * 32);

#define GEMM_COMPUTE(buf)                                                    \
  {                                                                          \
    const unsigned short* sA = &As[buf][0];                                  \
    const unsigned short* sB = &Bs[buf][0];                                  \
    short8 af[4], bfr[4];                                                    \
    _Pragma("unroll") for (int m = 0; m < 4; ++m)                            \
        af[m] = *(const short8*)&sA[(arow + m * 16) * 32 + kksw];            \
    _Pragma("unroll") for (int n = 0; n < 4; ++n)                            \
        bfr[n] = *(const short8*)&sB[(brow + n * 16) * 32 + kksw];           \
    _Pragma("unroll") for (int m = 0; m < 4; ++m)                            \
      _Pragma("unroll") for (int n = 0; n < 4; ++n)                          \
        acc[m][n] = __builtin_amdgcn_mfma_f32_16x16x32_bf16(                 \
            af[m], bfr[n], acc[m][n], 0, 0, 0);                              \
  }

#define GEMM_LOOP(KD)                                                        \
  GEMM_STAGE(0, 0, KD)                                                       \
  __syncthreads();                                                           \
  for (int k0 = 0; k0 < (KD); k0 += 64) {                                    \
    GEMM_STAGE(1, k0 + 32, KD)                                               \
    GEMM_COMPUTE(0)                                                          \
    __syncthreads();                                                         \
    if (k0 + 64 < (KD)) { GEMM_STAGE(0, k0 + 64, KD) }                       \
    GEMM_COMPUTE(1)                                                          \
    __syncthreads();                                                         \
  }

#define GEMM_PREAMBLE                                                        \
  __shared__ __align__(16) unsigned short As[2][128 * 32];                   \
  __shared__ __align__(16) unsigned short Bs[2][128 * 32];                   \
  const int tid = threadIdx.x;                                               \
  const int lane = tid & 63, w = tid >> 6;                                   \
  const int wr = w >> 1, wc = w & 1;                                         \
  const int sr = lane >> 2;                                                  \
  const int sc = (((lane & 3) ^ ((lane >> 3) & 3)) * 8); /* swizzled src */  \
  const int arow = wr * 64 + (lane & 15);                                    \
  const int brow = wc * 64 + (lane & 15);                                    \
  const int kksw = (((lane >> 4) ^ ((lane >> 1) & 3)) * 8); /* swz read */   \
  unsigned short* lA = &As[0][(w * 32) * 32];                                \
  unsigned short* lB = &Bs[0][(w * 32) * 32];

// fused q/k/v projection: blockIdx.z selects which; grid (8,32,3)
__global__ __launch_bounds__(256) void gemm_qkv(
    const unsigned short* __restrict__ lnq, const unsigned short* __restrict__ lnk,
    const unsigned short* __restrict__ lnv, const unsigned short* __restrict__ WqT,
    const unsigned short* __restrict__ WkT, const unsigned short* __restrict__ WvT,
    unsigned short* __restrict__ qf, unsigned short* __restrict__ kf,
    unsigned short* __restrict__ vh) {
  const int z = blockIdx.z;
  const unsigned short* A = z == 0 ? lnq : z == 1 ? lnk : lnv;
  const unsigned short* Bt = z == 0 ? WqT : z == 1 ? WkT : WvT;
  unsigned short* outb = z == 0 ? qf : z == 1 ? kf : vh;
  const int K = 1024, N = 1024;
  GEMM_PREAMBLE
  int bx, by;
  xcd_swizzle(bx, by);
  const int row0 = by * 128, col0 = bx * 128;
  const unsigned short* gA0 = A + (size_t)(row0 + w * 32 + sr) * K + sc;
  const unsigned short* gA1 = gA0 + (size_t)16 * K;
  const unsigned short* gB = Bt + (size_t)(col0 + w * 32 + sr) * K + sc;
  f32x4 acc[4][4] = {};
  GEMM_LOOP(1024)
#pragma unroll
  for (int m = 0; m < 4; ++m) {
    const int rbase = row0 + wr * 64 + m * 16 + (lane >> 4) * 4;
#pragma unroll
    for (int n = 0; n < 4; ++n) {
      const int c = col0 + wc * 64 + n * 16 + (lane & 15);
#pragma unroll
      for (int r = 0; r < 4; ++r) {
        float v = acc[m][n][r];
        if (z < 2) v = v > 0.f ? v + 1.f : __expf(v);  // elu+1
        outb[(size_t)(rbase + r) * N + c] = f2bf(v);
      }
    }
  }
}

// Wo projection + bias + residual -> qres (f32); grid (8,32)
__global__ __launch_bounds__(256) void gemm_wo(
    const unsigned short* __restrict__ A, const unsigned short* __restrict__ Bt,
    float* __restrict__ outf, const float* __restrict__ bias,
    const float* __restrict__ addm) {
  const int K = 1024, N = 1024;
  GEMM_PREAMBLE
  int bx, by;
  xcd_swizzle(bx, by);
  const int row0 = by * 128, col0 = bx * 128;
  const unsigned short* gA0 = A + (size_t)(row0 + w * 32 + sr) * K + sc;
  const unsigned short* gA1 = gA0 + (size_t)16 * K;
  const unsigned short* gB = Bt + (size_t)(col0 + w * 32 + sr) * K + sc;
  f32x4 acc[4][4] = {};
  GEMM_LOOP(1024)
#pragma unroll
  for (int m = 0; m < 4; ++m) {
    const int rbase = row0 + wr * 64 + m * 16 + (lane >> 4) * 4;
#pragma unroll
    for (int n = 0; n < 4; ++n) {
      const int c = col0 + wc * 64 + n * 16 + (lane & 15);
#pragma unroll
      for (int r = 0; r < 4; ++r) {
        const size_t idx = (size_t)(rbase + r) * N + c;
        outf[idx] = acc[m][n][r] + bias[c] + addm[idx];
      }
    }
  }
}

// ---------------- gathered MoE GEMM (Core A; phase-2 writes bf16 slots) ----------------
template <int PHASE>
__global__ __launch_bounds__(256) void gemm_moe(
    const unsigned short* __restrict__ Asrc, const unsigned short* __restrict__ Ball,
    const float* __restrict__ bias_all,
    const int* __restrict__ seg, const int* __restrict__ tok,
    const float* __restrict__ wgt, const int* __restrict__ slt,
    unsigned short* __restrict__ Hb, unsigned short* __restrict__ eoSb) {
  constexpr int K = (PHASE == 1) ? 1024 : 2048;
  constexpr int N = (PHASE == 1) ? 2048 : 1024;
  GEMM_PREAMBLE
  int bx, by;
  xcd_swizzle(bx, by);
  const int row0 = by * 128;
  if (row0 >= seg[8]) return;
  int e = 0;
  while (e < 7 && row0 >= seg[e + 1]) ++e;
  const int col0 = bx * 128;
  const unsigned short* Bt = Ball + (size_t)e * N * K;
  const int gr0 = row0 + w * 32 + sr;
  const int gr1 = gr0 + 16;
  const unsigned short* gA0;
  const unsigned short* gA1;
  if constexpr (PHASE == 1) {
    const int t0 = tok[gr0], t1 = tok[gr1];
    gA0 = Asrc + (size_t)(t0 < 0 ? 0 : t0) * K + sc;
    gA1 = Asrc + (size_t)(t1 < 0 ? 0 : t1) * K + sc;
  } else {
    gA0 = Asrc + (size_t)gr0 * K + sc;
    gA1 = Asrc + (size_t)gr1 * K + sc;
  }
  const unsigned short* gB = Bt + (size_t)(col0 + w * 32 + sr) * K + sc;
  f32x4 acc[4][4] = {};
  if constexpr (PHASE == 1) { GEMM_LOOP(1024) }
  else { GEMM_LOOP(2048) }
  const float* bias = bias_all + (size_t)e * N;
#pragma unroll
  for (int m = 0; m < 4; ++m) {
    const int rloc = wr * 64 + m * 16 + (lane >> 4) * 4;
#pragma unroll
    for (int n = 0; n < 4; ++n) {
      const int c = col0 + wc * 64 + n * 16 + (lane & 15);
#pragma unroll
      for (int r = 0; r < 4; ++r) {
        const int gr = row0 + rloc + r;
        float v = acc[m][n][r] + bias[c];
        if constexpr (PHASE == 1) {
          // gelu via tanh-form: v*sigmoid(1.59577v + 0.071355v^3); max dev ~1e-3
          float t2 = v * (1.59576912f + 0.07135481f * v * v);
          t2 = fminf(t2, 30.f);
          const float eg = __expf(t2);
          v = v * eg * __builtin_amdgcn_rcpf(eg + 1.f);
          Hb[(size_t)gr * 2048 + c] = f2bf(v);
        } else {
          const int tkn = tok[gr];
          if (tkn >= 0)
            eoSb[(size_t)slt[gr] * (4096 * 1024) + (size_t)tkn * 1024 + c] =
                f2bf(wgt[gr] * v);
        }
      }
    }
  }
}

// ---------------- attention: kv partials (bf16 partial store) ----------------
__global__ __launch_bounds__(256) void kvpart_kernel(
    const unsigned short* __restrict__ kf, const unsigned short* __restrict__ vh,
    unsigned short* __restrict__ kvp, float* __restrict__ ksp) {
  const int bh = blockIdx.x;
  const int b = bh >> 3, h = bh & 7;
  const int ch = blockIdx.y;
  const int tid = threadIdx.x;
  const int d0 = (tid >> 4) * 8, e0 = (tid & 15) * 8;
  __shared__ unsigned short kb[64][128];
  __shared__ unsigned short vb[64][128];
  for (int i = tid; i < 1024; i += 256) {
    const int tt = i >> 4, dd = (i & 15) * 8;
    const size_t base = ((size_t)((b * 1024 + ch * 64 + tt) * 8 + h)) * 128 + dd;
    *(short8*)&kb[tt][dd] = *(const short8*)&kf[base];
    *(short8*)&vb[tt][dd] = *(const short8*)&vh[base];
  }
  __syncthreads();
  float acc[8][8] = {};
  float ks[8] = {};
  for (int tt = 0; tt < 64; ++tt) {
    float kv8[8], vv8[8];
    const short8 kr = *(const short8*)&kb[tt][d0];
    const short8 vr = *(const short8*)&vb[tt][e0];
#pragma unroll
    for (int j = 0; j < 8; ++j) {
      kv8[j] = bf2f((unsigned short)kr[j]);
      vv8[j] = bf2f((unsigned short)vr[j]);
    }
#pragma unroll
    for (int i = 0; i < 8; ++i)
#pragma unroll
      for (int j = 0; j < 8; ++j) acc[i][j] += kv8[i] * vv8[j];
    if ((tid & 15) == 0)
#pragma unroll
      for (int i = 0; i < 8; ++i) ks[i] += kv8[i];
  }
  const size_t obase = ((size_t)(ch * 32 + bh) * 128) * 128;
#pragma unroll
  for (int i = 0; i < 8; ++i)
#pragma unroll
    for (int j = 0; j < 8; ++j)
      kvp[obase + (size_t)(d0 + i) * 128 + e0 + j] = f2bf(acc[i][j]);
  if ((tid & 15) == 0)
#pragma unroll
    for (int i = 0; i < 8; ++i) ksp[(size_t)(ch * 32 + bh) * 128 + d0 + i] = ks[i];
}

__global__ __launch_bounds__(256) void kvreduce_kernel(
    const unsigned short* __restrict__ kvp, const float* __restrict__ ksp,
    unsigned short* __restrict__ kvb, float* __restrict__ ksum) {
  const int idx = blockIdx.x * 256 + threadIdx.x;
  const int CS = 32 * 128 * 128;
  float s = 0.f;
#pragma unroll
  for (int c = 0; c < 16; ++c) s += bf2f(kvp[(size_t)c * CS + idx]);
  kvb[idx] = f2bf(s);
  if (idx < 32 * 128) {
    float t = 1e-6f;
#pragma unroll
    for (int c = 0; c < 16; ++c) t += ksp[c * 4096 + idx];
    ksum[idx] = t;
  }
}

__global__ __launch_bounds__(256) void attnout_kernel(
    const unsigned short* __restrict__ qf, const unsigned short* __restrict__ kvb,
    const float* __restrict__ ksum, unsigned short* __restrict__ ctx) {
  const int bh = blockIdx.x, b = bh >> 3, h = bh & 7;
  const int tb = blockIdx.y;
  const int tid = threadIdx.x;
  __shared__ unsigned short kvl[128 * 128];
  __shared__ float ksl[128];
  __shared__ float denom[128];
  __shared__ unsigned short qfl[128 * 32];
  for (int i = tid; i < 16384; i += 256) kvl[i] = kvb[(size_t)bh * 16384 + i];
  if (tid < 128) ksl[tid] = ksum[bh * 128 + tid];
  __syncthreads();
  if (tid < 128) {
    const int t = tb * 128 + tid;
    const size_t qbase = ((size_t)((b * 1024 + t) * 8 + h)) * 128;
    float s = 0.f;
    for (int d = 0; d < 128; ++d) s += bf2f(qf[qbase + d]) * ksl[d];
    denom[tid] = s;
  }
  float acc[8][8] = {};
  const int t0 = (tid >> 4) * 8, e0 = (tid & 15) * 8;
  for (int dc = 0; dc < 128; dc += 32) {
    __syncthreads();
    for (int i = tid; i < 128 * 32; i += 256) {
      const int tt = i >> 5, dd = i & 31;
      qfl[i] = qf[((size_t)((b * 1024 + tb * 128 + tt) * 8 + h)) * 128 + dc + dd];
    }
    __syncthreads();
    for (int dd = 0; dd < 32; ++dd) {
      float kvrow[8];
#pragma unroll
      for (int j = 0; j < 8; ++j) kvrow[j] = bf2f(kvl[(dc + dd) * 128 + e0 + j]);
#pragma unroll
      for (int i = 0; i < 8; ++i) {
        const float qv = bf2f(qfl[(t0 + i) * 32 + dd]);
#pragma unroll
        for (int j = 0; j < 8; ++j) acc[i][j] += qv * kvrow[j];
      }
    }
  }
  __syncthreads();
#pragma unroll
  for (int i = 0; i < 8; ++i) {
    const int t = tb * 128 + t0 + i;
    const float inv = 1.f / denom[t0 + i];
#pragma unroll
    for (int j = 0; j < 8; ++j)
      ctx[((size_t)(b * 1024 + t)) * 1024 + h * 128 + e0 + j] = f2bf(acc[i][j] * inv);
  }
}

// ---------------- host launcher ----------------
extern "C" void kernel_launch(void* const* d_in, const int* in_sizes, int n_in,
                              void* d_out, int out_size, void* d_ws, size_t ws_size,
                              hipStream_t stream) {
  (void)in_sizes; (void)n_in; (void)out_size; (void)ws_size;
  const float* vin  = (const float*)d_in[0];
  const float* kin  = (const float*)d_in[1];
  const float* qin  = (const float*)d_in[2];
  const float* noise = (const float*)d_in[3];
  const float* g_v = (const float*)d_in[4];  const float* b_v = (const float*)d_in[5];
  const float* g_k = (const float*)d_in[6];  const float* b_k = (const float*)d_in[7];
  const float* g_q = (const float*)d_in[8];  const float* b_q = (const float*)d_in[9];
  const float* g_moe = (const float*)d_in[10]; const float* b_moe = (const float*)d_in[11];
  const float* g_out = (const float*)d_in[12]; const float* b_out = (const float*)d_in[13];
  const float* Wq = (const float*)d_in[14];
  const float* Wk = (const float*)d_in[15];
  const float* Wv = (const float*)d_in[16];
  const float* Wo = (const float*)d_in[17];
  const float* bo = (const float*)d_in[18];
  const float* Wr = (const float*)d_in[19];
  const float* br = (const float*)d_in[20];
  const float* W1 = (const float*)d_in[21];
  const float* b1 = (const float*)d_in[22];
  const float* W2 = (const float*)d_in[23];
  const float* b2 = (const float*)d_in[24];
  float* out = (float*)d_out;

  const int NT = 4096, D = 1024, FF = 2048;
  const int MAXR = 9216;

  char* p = (char*)d_ws;
  auto alloc = [&](size_t bytes) {
    void* r = (void*)p;
    p += (bytes + 255) & ~(size_t)255;
    return r;
  };
  char* base0 = p;
  unsigned short* lnq = (unsigned short*)alloc((size_t)NT * D * 2);
  unsigned short* lnk = (unsigned short*)alloc((size_t)NT * D * 2);
  unsigned short* lnv = (unsigned short*)alloc((size_t)NT * D * 2);
  unsigned short* WqT = (unsigned short*)alloc((size_t)D * D * 2);
  unsigned short* WkT = (unsigned short*)alloc((size_t)D * D * 2);
  unsigned short* WvT = (unsigned short*)alloc((size_t)D * D * 2);
  unsigned short* WoT = (unsigned short*)alloc((size_t)D * D * 2);
  unsigned short* qf  = (unsigned short*)alloc((size_t)NT * D * 2);
  unsigned short* kf  = (unsigned short*)alloc((size_t)NT * D * 2);
  unsigned short* vh  = (unsigned short*)alloc((size_t)NT * D * 2);
  unsigned short* kvb = (unsigned short*)alloc((size_t)32 * 128 * 128 * 2);
  float* ksp  = (float*)alloc((size_t)16 * 32 * 128 * 4);
  float* ksum = (float*)alloc((size_t)32 * 128 * 4);
  unsigned short* ctx = (unsigned short*)alloc((size_t)NT * D * 2);
  float* qres = (float*)alloc((size_t)NT * D * 4);  // f32: routing needs exact picks
  unsigned short* xb = (unsigned short*)alloc((size_t)NT * D * 2);
  unsigned short* W1T_all = (unsigned short*)alloc((size_t)8 * D * FF * 2);
  unsigned short* W2T_all = (unsigned short*)alloc((size_t)8 * FF * D * 2);
  unsigned short* kvp = (unsigned short*)alloc((size_t)16 * 32 * 128 * 128 * 2);
  unsigned short* eoSb = (unsigned short*)alloc((size_t)2 * NT * D * 2);
  int* pick = (int*)alloc((size_t)NT * 2 * 4);
  float* pw = (float*)alloc((size_t)NT * 2 * 4);
  int* seg = (int*)alloc(9 * 4);
  int* tokl = (int*)alloc(MAXR * 4);
  float* wgt = (float*)alloc(MAXR * 4);
  int* slt = (int*)alloc(MAXR * 4);
  unsigned short* Hb = (unsigned short*)base0;  // 36MB alias over dead early bufs

  // 1) fused prep: all weight transposes + LN(q,k,v)
  prep_kernel<<<dim3(49152), 256, 0, stream>>>(
      qin, kin, vin, g_q, b_q, g_k, b_k, g_v, b_v, Wq, Wk, Wv, Wo, W1, W2,
      lnq, lnk, lnv, WqT, WkT, WvT, WoT, W1T_all, W2T_all);

  // 2) fused q/k/v projections (Core A, 768 blocks)
  gemm_qkv<<<dim3(D / 128, NT / 128, 3), 256, 0, stream>>>(lnq, lnk, lnv, WqT, WkT, WvT,
                                                           qf, kf, vh);

  // 3) linear attention state
  kvpart_kernel<<<dim3(32, 16), 256, 0, stream>>>(kf, vh, kvp, ksp);
  kvreduce_kernel<<<dim3(2048), 256, 0, stream>>>(kvp, ksp, kvb, ksum);
  attnout_kernel<<<dim3(32, 8), 256, 0, stream>>>(qf, kvb, ksum, ctx);

  // 4) out projection + bias + residual q -> q_res (f32)
  gemm_wo<<<dim3(D / 128, NT / 128), 256, 0, stream>>>(ctx, WoT, qres, bo, qin);

  // 5) fused MoE pre-LN/router + single-block routing build
  ln_moe_router_kernel<<<dim3(NT), 256, 0, stream>>>(qres, g_moe, b_moe, Wr, br, noise,
                                                     xb, pick, pw);
  route_build_kernel<<<dim3(1), 1024, 0, stream>>>(pick, pw, seg, tokl, wgt, slt);

  // 6) gathered expert GEMMs (Core A)
  gemm_moe<1><<<dim3(FF / 128, MAXR / 128), 256, 0, stream>>>(
      xb, W1T_all, b1, seg, tokl, wgt, slt, Hb, nullptr);
  gemm_moe<2><<<dim3(D / 128, MAXR / 128), 256, 0, stream>>>(
      Hb, W2T_all, b2, seg, tokl, wgt, slt, nullptr, eoSb);

  // 7) final residual LN
  final_kernel<<<dim3(NT), 256, 0, stream>>>(eoSb, xb, qres, g_out, b_out, out);
}